// Round 7
// baseline (524.535 us; speedup 1.0000x reference)
//
#include <hip/hip_runtime.h>

// HyperGANUpBlock (all fp32 I/O): x[4,8,32,32,128] -> up2 -> conv3^3(128->64, per-sample
// w1) -> BN(train,1e-3)+ReLU -> concat skip -> conv3^3(128->64, per-sample w2) -> BN+ReLU.
// R16: conv2 = R14 convf structure but B-fragments DIRECT FROM GLOBAL (conv1's proven
// pattern): W pre-transposed to wtg[b*27+tap][cq][co][8ci] (coalesced 256B segments,
// L1-hot: all 4 waves share each 16KB tap). Removes W staging + 45/63 barriers + 2/3 of
// LDS reads; LDS 50->33.8KB -> 4 blocks/CU (launch_bounds(256,4)).
// conv1 = parity-decomposition kernel (R14/15). Slotted BN stats + fin8.
// ws(fast): y1 32Mi | sums 8Ki | zb 256B | wtg 1.7Mi | (pad) | xb | skb | wc1.

typedef __attribute__((ext_vector_type(8))) short short8;
typedef __attribute__((ext_vector_type(4))) float f32x4;

__device__ __forceinline__ float bf2f(unsigned short u) {
  union { unsigned int i; float f; } v; v.i = ((unsigned int)u) << 16; return v.f;
}
__device__ __forceinline__ unsigned short f2b(float f) {
  union { float ff; unsigned int u; } v; v.ff = f;
  unsigned int x = v.u;
  return (unsigned short)((x + 0x7FFFu + ((x >> 16) & 1u)) >> 16);  // RNE
}
__device__ __forceinline__ unsigned int pk2(float a, float b) {
  return (unsigned int)f2b(a) | ((unsigned int)f2b(b) << 16);
}
__device__ __forceinline__ void gload16(const void* g, void* l) {
  __builtin_amdgcn_global_load_lds(
      (const __attribute__((address_space(1))) void*)g,
      (__attribute__((address_space(3))) void*)l, 16, 0, 0);
}

#define ASTR 136  // transpose-scratch row stride (shorts)
#define WSTR 132  // old-path W row stride (shorts)

// fallback: w[b,tap,ci,co] fp32 -> wt[b,tap,co,ci] bf16 ; 216 blocks
__global__ __launch_bounds__(256) void hg_wt_k(const float* __restrict__ w1,
                                               const float* __restrict__ w2,
                                               unsigned short* __restrict__ wt1,
                                               unsigned short* __restrict__ wt2) {
  __shared__ short T[64 * ASTR];
  int blk = blockIdx.x;
  int sel = blk >= 108;
  const float* w = sel ? w2 : w1;
  unsigned short* wt = sel ? wt2 : wt1;
  int bt = sel ? blk - 108 : blk;
  const float* src = w + (size_t)bt * 8192;
  int tid = threadIdx.x;
  int co = tid & 63;
  int c0 = tid >> 6;
  for (int i = 0; i < 32; ++i) {
    int ci = c0 + (i << 2);
    T[co * ASTR + ci] = (short)f2b(src[(size_t)ci * 64 + co]);
  }
  __syncthreads();
  unsigned short* dst = wt + (size_t)bt * 8192;
  for (int i = 0; i < 4; ++i) {
    int task = tid + (i << 8);          // 1024 tasks
    int row = task >> 4, q = task & 15;
    *(uint4*)(dst + row * 128 + (q << 3)) = *(const uint4*)&T[row * ASTR + (q << 3)];
  }
}

// fast path: w2[b,tap,ci,co] fp32 -> wtg[b*27+tap][cq][co][8ci] bf16 (fragment-major,
// lane-coalesced: 16 lanes x 16B = 256B contiguous per (cq,nt)). 108 blocks.
__global__ __launch_bounds__(256) void hg_wtg_k(const float* __restrict__ w2,
                                                unsigned short* __restrict__ wtg) {
  __shared__ short T[64 * ASTR];
  int bt = blockIdx.x;
  const float* src = w2 + (size_t)bt * 8192;
  int tid = threadIdx.x;
  int co = tid & 63;
  int c0 = tid >> 6;
  for (int i = 0; i < 32; ++i) {
    int ci = c0 + (i << 2);
    T[co * ASTR + ci] = (short)f2b(src[(size_t)ci * 64 + co]);
  }
  __syncthreads();
  unsigned short* dst = wtg + (size_t)bt * 8192;
  for (int i = 0; i < 4; ++i) {
    int task = tid + (i << 8);          // 1024 tasks: row=co, q=cq
    int row = task >> 4, q = task & 15;
    *(uint4*)(dst + ((q << 6) + row) * 8) = *(const uint4*)&T[row * ASTR + (q << 3)];
  }
}

// parity-combined conv1 weights: wc1[b][(pd2+td)*16+(ph2+th)*4+(pw2+tw)][co][ci] bf16
// S(0,0)={0} S(0,1)={1,2} S(1,0)={0,1} S(1,1)={2}. 256 blocks (4 b x 64 mats).
__global__ __launch_bounds__(256) void hg_wc1_k(const float* __restrict__ w1,
                                                unsigned short* __restrict__ wc1) {
  __shared__ short T[64 * ASTR];
  int blk = blockIdx.x;
  int b = blk >> 6, m = blk & 63;
  int dd = m >> 4, hh = (m >> 2) & 3, ww = m & 3;   // each = p*2+t
  const int ks[4] = {0, 1, 0, 2}, kc[4] = {1, 2, 2, 1};
  int tid = threadIdx.x, co = tid & 63, c0 = tid >> 6;
  const float* wb = w1 + (size_t)b * 27 * 8192;
  for (int i = 0; i < 32; ++i) {
    int ci = c0 + (i << 2);
    float s = 0.f;
    for (int a = 0; a < kc[dd]; ++a)
      for (int e = 0; e < kc[hh]; ++e)
        for (int c = 0; c < kc[ww]; ++c) {
          int tap = ((ks[dd] + a) * 3 + ks[hh] + e) * 3 + ks[ww] + c;
          s += wb[(size_t)tap * 8192 + (size_t)ci * 64 + co];
        }
    T[co * ASTR + ci] = (short)f2b(s);
  }
  __syncthreads();
  unsigned short* dst = wc1 + (size_t)blk * 8192;
  for (int i = 0; i < 4; ++i) {
    int task = tid + (i << 8);
    int row = task >> 4, q = task & 15;
    *(uint4*)(dst + row * 128 + (q << 3)) = *(const uint4*)&T[row * ASTR + (q << 3)];
  }
}

// ---------------- conv1: parity decomposition over source x ----------------
__global__ __launch_bounds__(256, 3) void hg_c1p_k(
    const unsigned short* __restrict__ xb, const unsigned short* __restrict__ wc1,
    const unsigned short* __restrict__ zb, unsigned short* __restrict__ outb,
    float* __restrict__ sums) {
  __shared__ short Xl[2 * 100 * 128];   // 51200 B: 2 planes x 10x10 cells x 128ch
  int tid = threadIdx.x;
  int xcd = blockIdx.x & 7, slot = blockIdx.x >> 3;   // 1024 blocks
  int b = xcd & 3;
  int t = ((xcd >> 2) << 7) + slot;     // 0..255
  int od = t >> 4, hti = (t >> 2) & 3, wti = t & 3;
  int pd = od & 1, md = od >> 1;
  int lane = tid & 63, quad = lane >> 4, l16 = lane & 15;
  int wid = tid >> 6;
  int ph = wid >> 1, pw = wid & 1;

  for (int pl = 0; pl < 2; ++pl) {
    int sd = md + pd - 1 + pl;
    int dok = ((unsigned)sd < 8u);
    for (int i = 0; i < 7; ++i) {
      int task = tid + (i << 8);
      if (task < 1600) {                // 100 pos x 16 chunks
        int pos = task >> 4, pq = task & 15;
        int q = (pq & 8) | ((pq & 7) ^ (pos & 7));
        int sh = pos / 10, sw = pos - sh * 10;
        int h = (hti << 3) + sh - 1, w = (wti << 3) + sw - 1;
        const unsigned short* src = zb;
        if (dok && (unsigned)h < 32u && (unsigned)w < 32u)
          src = xb + ((((size_t)(b * 8 + sd)) * 32 + h) * 32 + w) * 128 + (q << 3);
        gload16(src, (char*)Xl + ((pl * 1600 + (i << 8) + (tid & 192)) << 4));
      }
    }
  }
  __syncthreads();                      // the ONLY staging barrier

  f32x4 acc[4][4];
#pragma unroll
  for (int i = 0; i < 4; ++i)
#pragma unroll
    for (int j = 0; j < 4; ++j) acc[i][j] = (f32x4){0.f, 0.f, 0.f, 0.f};

  const unsigned short* wcb = wc1 + ((size_t)b * 64 + (pd << 5) + (ph << 3) + (pw << 1)) * 8192;

  for (int td = 0; td < 2; ++td) {
    const char* Xp = (const char*)Xl + td * 25600;
    for (int th = 0; th < 2; ++th) {
      int hb = ph + th;
      for (int tw = 0; tw < 2; ++tw) {
        int wb2 = pw + tw;
        const unsigned short* wp = wcb + (size_t)((td << 4) + (th << 2) + tw) * 8192;
#pragma unroll
        for (int ksx = 0; ksx < 4; ++ksx) {
          int cq = (ksx << 2) + quad;
          short8 av[4], bv[4];
#pragma unroll
          for (int mt = 0; mt < 4; ++mt) {
            int pos = ((mt << 1) + (l16 >> 3) + hb) * 10 + (l16 & 7) + wb2;
            int pc = (cq & 8) | ((cq & 7) ^ (pos & 7));
            av[mt] = *(const short8*)(Xp + pos * 256 + (pc << 4));
          }
#pragma unroll
          for (int nt = 0; nt < 4; ++nt)
            bv[nt] = *(const short8*)(wp + ((nt << 4) + l16) * 128 + (cq << 3));
#pragma unroll
          for (int mt = 0; mt < 4; ++mt)
#pragma unroll
            for (int nt = 0; nt < 4; ++nt)
              acc[mt][nt] = __builtin_amdgcn_mfma_f32_16x16x32_bf16(
                  av[mt], bv[nt], acc[mt][nt], 0, 0, 0);
        }
      }
    }
  }

  __syncthreads();                      // Xl reads done -> stats scratch
  float* sbf = (float*)Xl;
  int rowb = (b * 16 + od) * 64;
#pragma unroll
  for (int nt = 0; nt < 4; ++nt) {
    int n = (nt << 4) + l16;
    float s = 0.f, q2 = 0.f;
#pragma unroll
    for (int mt = 0; mt < 4; ++mt) {
      int mh = (mt << 1) + (quad >> 1);
      int oh = (((hti << 3) + mh) << 1) + ph;
      size_t rb = (size_t)(rowb + oh) * 64;
#pragma unroll
      for (int r = 0; r < 4; ++r) {
        float v = acc[mt][nt][r];
        int ow = (((wti << 3) + ((quad & 1) << 2) + r) << 1) + pw;
        outb[(rb + ow) * 64 + n] = f2b(v);
        s += v; q2 += v * v;
      }
    }
    s += __shfl_xor(s, 16); s += __shfl_xor(s, 32);
    q2 += __shfl_xor(q2, 16); q2 += __shfl_xor(q2, 32);
    if (quad == 0) { sbf[wid * 128 + n] = s; sbf[wid * 128 + 64 + n] = q2; }
  }
  __syncthreads();
  if (tid < 64) {
    float s = sbf[tid] + sbf[128 + tid] + sbf[256 + tid] + sbf[384 + tid];
    float q2 = sbf[64 + tid] + sbf[192 + tid] + sbf[320 + tid] + sbf[448 + tid];
    int sl = (blockIdx.x & 7) << 7;
    atomicAdd(&sums[sl + tid], s);
    atomicAdd(&sums[sl + 64 + tid], q2);
  }
}

// ---------------- R16 conv2: A in LDS, B direct from global (wtg) ----------------
__global__ __launch_bounds__(256, 4) void hg_c2g_k(
    const unsigned short* __restrict__ y1n, const unsigned short* __restrict__ skb,
    const unsigned short* __restrict__ wtg, const unsigned short* __restrict__ zb,
    float* __restrict__ outf, float* __restrict__ sums) {
  __shared__ short Al[132 * 128];  // 33792 B, unpadded, chunk-swizzled
  int tid = threadIdx.x;
  int xcd = blockIdx.x & 7, slot = blockIdx.x >> 3;
  int b = xcd & 3;
  int t = ((xcd >> 2) << 8) + slot;       // 0..511 tile within sample
  int m0 = (b << 16) + (t << 7);
  int od  = (t >> 5) & 15;
  int oh0 = (t << 1) & 63;
  int lane = tid & 63, quad = lane >> 4, l16 = lane & 15;
  int wm = (tid >> 6) << 5;               // wave row offset 0/32/64/96

  f32x4 acc[2][4];
  for (int i = 0; i < 2; ++i)
    for (int j = 0; j < 4; ++j) acc[i][j] = (f32x4){0.f, 0.f, 0.f, 0.f};

  const unsigned short* wb = wtg + (size_t)b * 27 * 8192;

  for (int kd = 0; kd < 3; ++kd) {
    int ud = od + kd - 1;
    int dok = ((unsigned)ud < 16u);
    for (int kh = 0; kh < 3; ++kh) {
      __syncthreads();  // prior MFMAs done reading Al
      for (int i = 0; i < 9; ++i) {
        int task = tid + (i << 8);
        if (task < 2112) {
          int pos = task >> 4, pq = task & 15;
          int q = (pq & 8) | ((pq & 7) ^ (pos & 7));  // logical chunk (involution)
          int g = (pos >= 66) ? 1 : 0;
          int uw = pos - (g ? 66 : 0) - 1;
          int uh = oh0 + g + kh - 1;
          const unsigned short* src = zb;
          if (dok && (unsigned)uh < 64u && (unsigned)uw < 64u) {
            size_t srow = (((size_t)(b * 16 + ud)) * 64 + uh) * 64 + uw;
            src = (q < 8) ? (y1n + srow * 64 + (q << 3))
                          : (skb + srow * 64 + ((q - 8) << 3));
          }
          gload16(src, (char*)Al + (((i << 8) + (tid & 192)) << 4));
        }
      }
      __syncthreads();  // drains vmcnt(0): A landed
#pragma clang loop unroll(disable)
      for (int kw = 0; kw < 3; ++kw) {
        const unsigned short* wp = wb + (size_t)((kd * 3 + kh) * 3 + kw) * 8192;
#pragma unroll
        for (int k0 = 0; k0 < 4; ++k0) {
          int cq = (k0 << 2) + quad;
          short8 av[2], bv[4];
#pragma unroll
          for (int mt = 0; mt < 2; ++mt) {
            int r = wm + (mt << 4) + l16;
            int pos = (r >> 6) * 66 + (r & 63) + kw;
            int pc = (cq & 8) | ((cq & 7) ^ (pos & 7));
            av[mt] = *(const short8*)((const char*)Al + pos * 256 + (pc << 4));
          }
#pragma unroll
          for (int nt = 0; nt < 4; ++nt)
            bv[nt] = *(const short8*)(wp + (((cq << 6) + (nt << 4) + l16) << 3));
#pragma unroll
          for (int mt = 0; mt < 2; ++mt)
#pragma unroll
            for (int nt = 0; nt < 4; ++nt)
              acc[mt][nt] = __builtin_amdgcn_mfma_f32_16x16x32_bf16(
                  av[mt], bv[nt], acc[mt][nt], 0, 0, 0);
        }
      }
    }
  }

  // epilogue + fused stats (slotted atomics)
  __syncthreads();                      // Al reads done -> scratch
  float* sbf = (float*)Al;
  for (int nt = 0; nt < 4; ++nt) {
    int n = (nt << 4) + l16;
    float s = 0.f, q2 = 0.f;
    for (int mt = 0; mt < 2; ++mt) {
      int mbase = m0 + wm + (mt << 4) + (quad << 2);
      for (int r = 0; r < 4; ++r) {
        float v = acc[mt][nt][r];
        outf[(size_t)(mbase + r) * 64 + n] = v;
        s += v; q2 += v * v;
      }
    }
    s += __shfl_xor(s, 16); s += __shfl_xor(s, 32);
    q2 += __shfl_xor(q2, 16); q2 += __shfl_xor(q2, 32);
    if (quad == 0) { sbf[(wm >> 5) * 128 + n] = s; sbf[(wm >> 5) * 128 + 64 + n] = q2; }
  }
  __syncthreads();
  if (tid < 64) {
    float s = sbf[tid] + sbf[128 + tid] + sbf[256 + tid] + sbf[384 + tid];
    float q2 = sbf[64 + tid] + sbf[192 + tid] + sbf[320 + tid] + sbf[448 + tid];
    int sl = (blockIdx.x & 7) << 7;
    atomicAdd(&sums[sl + tid], s);
    atomicAdd(&sums[sl + 64 + tid], q2);
  }
}

// ---------------- old conv kernel (fallback when ws too small) ----------------
__global__ __launch_bounds__(256) void hg_conv_o_k(
    const float* __restrict__ xf, const unsigned short* __restrict__ y1n,
    const float* __restrict__ skip, const float* __restrict__ wf,
    const unsigned short* __restrict__ wt, const float* __restrict__ bn,
    unsigned short* __restrict__ outb, float* __restrict__ outf,
    int mode, int has_wt) {
  __shared__ short Al[132 * ASTR];
  __shared__ short Wl[64 * WSTR];
  __shared__ float sbl[128];
  int tid = threadIdx.x;
  int xcd = blockIdx.x & 7, slot = blockIdx.x >> 3;
  int b = xcd & 3;
  int t = ((xcd >> 2) << 8) + slot;
  int m0 = (b << 16) + (t << 7);
  int od  = (t >> 5) & 15;
  int oh0 = (t << 1) & 63;
  int lane = tid & 63, quad = lane >> 4, l16 = lane & 15;
  int wm = (tid >> 6) << 5;

  if (mode == 1 && tid < 128) sbl[tid] = bn[tid];

  f32x4 acc[2][4];
  for (int i = 0; i < 2; ++i)
    for (int j = 0; j < 4; ++j) acc[i][j] = (f32x4){0.f, 0.f, 0.f, 0.f};

  const float* wbf = wf + (size_t)b * 27 * 8192;
  const unsigned short* wbt = wt + (size_t)b * 27 * 8192;

  for (int kd = 0; kd < 3; ++kd) {
    int ud = od + kd - 1;
    int dok = (ud >= 0 && ud < 16);
    for (int kh = 0; kh < 3; ++kh) {
      __syncthreads();
      for (int i = 0; i < 9; ++i) {
        int task = tid + (i << 8);
        if (task < 2112) {
          int chunk = task & 15;
          int pos = task >> 4;
          int g = (pos >= 66) ? 1 : 0;
          int uwi = pos - (g ? 66 : 0);
          int uh = oh0 + g + kh - 1;
          int uw = uwi - 1;
          uint4 val = make_uint4(0u, 0u, 0u, 0u);
          if (dok && (unsigned)uh < 64u && (unsigned)uw < 64u) {
            if (mode == 0) {
              size_t src = ((((size_t)(b * 8 + (ud >> 1))) * 32 + (uh >> 1)) * 32 +
                            (uw >> 1)) * 128 + (chunk << 3);
              float4 f0 = *(const float4*)(xf + src);
              float4 f1 = *(const float4*)(xf + src + 4);
              val.x = pk2(f0.x, f0.y); val.y = pk2(f0.z, f0.w);
              val.z = pk2(f1.x, f1.y); val.w = pk2(f1.z, f1.w);
            } else {
              size_t srow = (((size_t)(b * 16 + ud)) * 64 + uh) * 64 + uw;
              if (chunk < 8) {
                uint4 raw = *(const uint4*)(y1n + srow * 64 + (chunk << 3));
                unsigned int u[4] = {raw.x, raw.y, raw.z, raw.w};
                unsigned int o[4];
                int c0 = chunk << 3;
                for (int q = 0; q < 4; ++q) {
                  int c = c0 + q * 2;
                  float f0 = sbl[c] * bf2f((unsigned short)(u[q] & 0xFFFFu)) + sbl[64 + c];
                  float f1 = sbl[c + 1] * bf2f((unsigned short)(u[q] >> 16)) + sbl[64 + c + 1];
                  o[q] = pk2(f0 > 0.f ? f0 : 0.f, f1 > 0.f ? f1 : 0.f);
                }
                val = make_uint4(o[0], o[1], o[2], o[3]);
              } else {
                const float* sp = skip + srow * 64 + ((chunk - 8) << 3);
                float4 f0 = *(const float4*)(sp);
                float4 f1 = *(const float4*)(sp + 4);
                val.x = pk2(f0.x, f0.y); val.y = pk2(f0.z, f0.w);
                val.z = pk2(f1.x, f1.y); val.w = pk2(f1.z, f1.w);
              }
            }
          }
          *(uint4*)&Al[pos * ASTR + (chunk << 3)] = val;
        }
      }
      for (int kw = 0; kw < 3; ++kw) {
        if (kw) __syncthreads();
        int tap = (kd * 3 + kh) * 3 + kw;
        if (has_wt) {
          const unsigned short* wsrc = wbt + (size_t)tap * 8192;
          for (int i = 0; i < 4; ++i) {
            int task = tid + (i << 8);
            int co = task >> 4, q = task & 15;
            *(uint4*)&Wl[co * WSTR + (q << 3)] = *(const uint4*)(wsrc + co * 128 + (q << 3));
          }
        } else {
          const float* wp = wbf + (size_t)tap * 8192 + (tid & 63);
          int wco = tid & 63;
          int ci0 = (tid >> 6) << 5;
          for (int c = 0; c < 32; c += 2) {
            float f0 = wp[(size_t)(ci0 + c) * 64];
            float f1 = wp[(size_t)(ci0 + c + 1) * 64];
            *(unsigned int*)&Wl[wco * WSTR + ci0 + c] = pk2(f0, f1);
          }
        }
        __syncthreads();
        for (int k0 = 0; k0 < 128; k0 += 32) {
          int kk = k0 + (quad << 3);
          union { uint4 u; short8 s; } cv;
          short8 av[2];
          for (int mt = 0; mt < 2; ++mt) {
            int r = wm + (mt << 4) + l16;
            int g = r >> 6, ow = r & 63;
            cv.u = *(const uint4*)&Al[(g * 66 + ow + kw) * ASTR + kk];
            av[mt] = cv.s;
          }
          short8 bv[4];
          for (int nt = 0; nt < 4; ++nt) {
            int base = ((nt << 4) + l16) * WSTR + kk;
            uint2 lo = *(const uint2*)&Wl[base];
            uint2 hi = *(const uint2*)&Wl[base + 4];
            cv.u = make_uint4(lo.x, lo.y, hi.x, hi.y);
            bv[nt] = cv.s;
          }
          for (int mt = 0; mt < 2; ++mt)
            for (int nt = 0; nt < 4; ++nt)
              acc[mt][nt] = __builtin_amdgcn_mfma_f32_16x16x32_bf16(
                  av[mt], bv[nt], acc[mt][nt], 0, 0, 0);
        }
      }
    }
  }

  for (int mt = 0; mt < 2; ++mt) {
    int mbase = m0 + wm + (mt << 4) + (quad << 2);
    for (int nt = 0; nt < 4; ++nt) {
      int n = (nt << 4) + l16;
      for (int r = 0; r < 4; ++r) {
        float v = acc[mt][nt][r];
        size_t o = (size_t)(mbase + r) * 64 + n;
        if (mode == 0) outb[o] = f2b(v);
        else outf[o] = v;
      }
    }
  }
}

__global__ void hg_zero_k(float* __restrict__ p, int n) {
  for (int i = threadIdx.x; i < n; i += 256) p[i] = 0.f;
}

// fallback-path stats
__global__ __launch_bounds__(256) void hg_stats_k(const unsigned short* __restrict__ yb,
                                                  const float* __restrict__ yf, int isf,
                                                  float* __restrict__ sums) {
  int t = threadIdx.x;
  int c = t & 63;
  int r0 = blockIdx.x * 4 + (t >> 6);
  float sum = 0.f, ss = 0.f;
  for (int r = r0; r < 262144; r += 4096) {
    size_t idx = (size_t)r * 64 + c;
    float v = isf ? yf[idx] : bf2f(yb[idx]);
    sum += v; ss += v * v;
  }
  atomicAdd(&sums[c], sum);
  atomicAdd(&sums[64 + c], ss);
}

// fallback finalize (single-slot)
__global__ void hg_fin_k(float* __restrict__ sb, const float* __restrict__ gm,
                         const float* __restrict__ bt) {
  int c = threadIdx.x;  // 64
  float invN = 1.f / 262144.f;
  float mean = sb[c] * invN;
  float var  = sb[64 + c] * invN - mean * mean;
  float sc = gm[c] * rsqrtf(var + 1e-3f);
  sb[c] = sc;
  sb[64 + c] = bt[c] - mean * sc;
}

// fast-path finalize: reduce 8 slots of {sum[64], ss[64]} -> slot0 {scale, shift}
__global__ void hg_fin8_k(float* __restrict__ sb, const float* __restrict__ gm,
                          const float* __restrict__ bt) {
  int c = threadIdx.x;  // 64
  float s = 0.f, q2 = 0.f;
  for (int k = 0; k < 8; ++k) { s += sb[(k << 7) + c]; q2 += sb[(k << 7) + 64 + c]; }
  float invN = 1.f / 262144.f;
  float mean = s * invN;
  float var  = q2 * invN - mean * mean;
  float sc = gm[c] * rsqrtf(var + 1e-3f);
  sb[c] = sc;
  sb[64 + c] = bt[c] - mean * sc;
}

// fp32 -> bf16, 8 elements/thread
__global__ __launch_bounds__(256) void hg_cvt_k(const float* __restrict__ s,
                                                unsigned short* __restrict__ d) {
  size_t i = ((size_t)blockIdx.x * 256 + threadIdx.x) << 3;
  float4 a = *(const float4*)(s + i);
  float4 c = *(const float4*)(s + i + 4);
  uint4 o;
  o.x = pk2(a.x, a.y); o.y = pk2(a.z, a.w);
  o.z = pk2(c.x, c.y); o.w = pk2(c.z, c.w);
  *(uint4*)(d + i) = o;
}

// BN1+ReLU in place on bf16 y1 (channel = idx % 64)
__global__ __launch_bounds__(256) void hg_bnb_k(unsigned short* __restrict__ y,
                                                const float* __restrict__ sb) {
  size_t i = ((size_t)blockIdx.x * 256 + threadIdx.x) << 3;
  int c0 = (int)(i & 63);
  uint4 v = *(uint4*)(y + i);
  unsigned int u[4] = {v.x, v.y, v.z, v.w};
  for (int q = 0; q < 4; ++q) {
    int c = c0 + q * 2;
    float f0 = sb[c] * bf2f((unsigned short)(u[q] & 0xFFFFu)) + sb[64 + c];
    float f1 = sb[c + 1] * bf2f((unsigned short)(u[q] >> 16)) + sb[64 + c + 1];
    u[q] = pk2(f0 > 0.f ? f0 : 0.f, f1 > 0.f ? f1 : 0.f);
  }
  *(uint4*)(y + i) = make_uint4(u[0], u[1], u[2], u[3]);
}

__global__ __launch_bounds__(256) void hg_bnrelu_f_k(float* __restrict__ y,
                                                     const float* __restrict__ sb) {
  size_t i = (size_t)blockIdx.x * 256 + threadIdx.x;  // float4 index
  int c4 = ((int)i & 15) << 2;
  float4 v = *(float4*)(y + i * 4);
  float f;
  f = sb[c4]     * v.x + sb[64 + c4];     v.x = f > 0.f ? f : 0.f;
  f = sb[c4 + 1] * v.y + sb[64 + c4 + 1]; v.y = f > 0.f ? f : 0.f;
  f = sb[c4 + 2] * v.z + sb[64 + c4 + 2]; v.z = f > 0.f ? f : 0.f;
  f = sb[c4 + 3] * v.w + sb[64 + c4 + 3]; v.w = f > 0.f ? f : 0.f;
  *(float4*)(y + i * 4) = v;
}

extern "C" void kernel_launch(void* const* d_in, const int* in_sizes, int n_in,
                              void* d_out, int out_size, void* d_ws, size_t ws_size,
                              hipStream_t stream) {
  (void)out_size;
  int ix = 0, iw1 = 1, iw2 = 2, isk = 3, ig1 = 4, ib1 = 5, ig2 = 6, ib2 = 7;
  if (n_in >= 9 && in_sizes[0] == 4194304 && in_sizes[1] == 884736 &&
      in_sizes[3] == 16777216 && in_sizes[4] == 64) {
    // insertion order
  } else if (n_in >= 9 && in_sizes[0] == 64 && in_sizes[4] == 16777216 &&
             in_sizes[6] == 884736 && in_sizes[8] == 4194304) {
    ib1 = 0; ib2 = 1; ig1 = 2; ig2 = 3; isk = 4; iw1 = 6; iw2 = 7; ix = 8;
  } else {
    return;
  }
  if (ws_size < (32ull << 20) + 2048ull) return;

  const float* x    = (const float*)d_in[ix];
  const float* w1   = (const float*)d_in[iw1];
  const float* w2   = (const float*)d_in[iw2];
  const float* skip = (const float*)d_in[isk];
  const float* g1   = (const float*)d_in[ig1];
  const float* b1   = (const float*)d_in[ib1];
  const float* g2   = (const float*)d_in[ig2];
  const float* b2   = (const float*)d_in[ib2];
  float* out = (float*)d_out;

  // fast-path layout
  const size_t OFF_SUMS = 32ull << 20;            // 8 KiB: 2 layers x 8 slots x 128 f32
  const size_t OFF_ZB   = OFF_SUMS + 8192;        // zero16 region (256 B)
  const size_t OFF_WT1  = OFF_ZB + 256;           // wtg (fast) / wt1 (fallback)
  const size_t OFF_WT2  = OFF_WT1 + 1769472;
  const size_t OFF_XB   = OFF_WT2 + 1769472;
  const size_t OFF_SKB  = OFF_XB + 8388608;       // 4194304 bf16
  const size_t OFF_WC1  = OFF_SKB + 33554432;     // 16777216 bf16
  const size_t NEED     = OFF_WC1 + 4194304;      // ~79.4 MB

  unsigned short* y1 = (unsigned short*)d_ws;     // 32 MiB bf16

  if (ws_size >= NEED) {
    // -------- fast path: parity conv1 + global-B conv2, slotted fused stats --------
    float* sums  = (float*)((char*)d_ws + OFF_SUMS);
    float* sums1 = sums;                          // 8 slots x 128
    float* sums2 = sums + 1024;                   // 8 slots x 128
    unsigned short* zb  = (unsigned short*)((char*)d_ws + OFF_ZB);
    unsigned short* wtg = (unsigned short*)((char*)d_ws + OFF_WT1);
    unsigned short* xb  = (unsigned short*)((char*)d_ws + OFF_XB);
    unsigned short* skb = (unsigned short*)((char*)d_ws + OFF_SKB);
    unsigned short* wc1 = (unsigned short*)((char*)d_ws + OFF_WC1);

    hg_zero_k<<<1, 256, 0, stream>>>(sums, 2112);  // sums 2048 + zb 64 floats
    hg_wtg_k<<<108, 256, 0, stream>>>(w2, wtg);
    hg_wc1_k<<<256, 256, 0, stream>>>(w1, wc1);
    hg_cvt_k<<<2048, 256, 0, stream>>>(x, xb);
    hg_cvt_k<<<8192, 256, 0, stream>>>(skip, skb);
    hg_c1p_k<<<1024, 256, 0, stream>>>(xb, wc1, zb, y1, sums1);
    hg_fin8_k<<<1, 64, 0, stream>>>(sums1, g1, b1);
    hg_bnb_k<<<8192, 256, 0, stream>>>(y1, sums1);  // BN1+ReLU in place
    hg_c2g_k<<<2048, 256, 0, stream>>>(y1, skb, wtg, zb, out, sums2);
    hg_fin8_k<<<1, 64, 0, stream>>>(sums2, g2, b2);
    hg_bnrelu_f_k<<<16384, 256, 0, stream>>>(out, sums2);
  } else {
    // -------- fallback: R9 path (original layout) --------
    float* sums  = (float*)((char*)d_ws + (32ull << 20));
    float* sums1 = sums;
    float* sums2 = sums + 128;
    unsigned short* wt1 = (unsigned short*)((char*)d_ws + (32ull << 20) + 2048ull);
    unsigned short* wt2 = wt1 + 884736ull;
    const size_t WS_NEED = (32ull << 20) + 2048ull + 2ull * 884736ull * 2ull;
    int has_wt = (ws_size >= WS_NEED) ? 1 : 0;

    hg_zero_k<<<1, 256, 0, stream>>>(sums, 512);
    if (has_wt) hg_wt_k<<<216, 256, 0, stream>>>(w1, w2, wt1, wt2);
    hg_conv_o_k<<<2048, 256, 0, stream>>>(x, y1, skip, w1, wt1, sums1, y1, out, 0, has_wt);
    hg_stats_k<<<1024, 256, 0, stream>>>(y1, out, 0, sums1);
    hg_fin_k<<<1, 64, 0, stream>>>(sums1, g1, b1);
    hg_conv_o_k<<<2048, 256, 0, stream>>>(x, y1, skip, w2, wt2, sums1, y1, out, 1, has_wt);
    hg_stats_k<<<1024, 256, 0, stream>>>(y1, out, 1, sums2);
    hg_fin_k<<<1, 64, 0, stream>>>(sums2, g2, b2);
    hg_bnrelu_f_k<<<16384, 256, 0, stream>>>(out, sums2);
  }
}

// Round 8
// 423.456 us; speedup vs baseline: 1.2387x; 1.2387x over previous
//
#include <hip/hip_runtime.h>

// HyperGANUpBlock (all fp32 I/O): x[4,8,32,32,128] -> up2 -> conv3^3(128->64, per-sample
// w1) -> BN(train,1e-3)+ReLU -> concat skip -> conv3^3(128->64, per-sample w2) -> BN+ReLU.
// R17: launch-count attack. conv2 REVERTED to R14 convf (175us, best measured; R15/R16
// restructures both lost: occupancy > reuse, and global-B thrashes L2 under streaming A).
// Prep fused into ONE kernel (zero|wt2|wc1|cvt-x|cvt-skip via block-range dispatch);
// fin8 folded into bnb/bnrelu consumers. Fast path = 5 dispatches (was 12).
// conv1 = parity decomposition (27->8 taps). Slotted BN stats (8x128) in conv epilogues.
// ws(fast): y1 32Mi | sums 8Ki | zb 256B | wt2 1.7Mi | (spare) | xb | skb | wc1.

typedef __attribute__((ext_vector_type(8))) short short8;
typedef __attribute__((ext_vector_type(4))) float f32x4;

__device__ __forceinline__ float bf2f(unsigned short u) {
  union { unsigned int i; float f; } v; v.i = ((unsigned int)u) << 16; return v.f;
}
__device__ __forceinline__ unsigned short f2b(float f) {
  union { float ff; unsigned int u; } v; v.ff = f;
  unsigned int x = v.u;
  return (unsigned short)((x + 0x7FFFu + ((x >> 16) & 1u)) >> 16);  // RNE
}
__device__ __forceinline__ unsigned int pk2(float a, float b) {
  return (unsigned int)f2b(a) | ((unsigned int)f2b(b) << 16);
}
__device__ __forceinline__ void gload16(const void* g, void* l) {
  __builtin_amdgcn_global_load_lds(
      (const __attribute__((address_space(1))) void*)g,
      (__attribute__((address_space(3))) void*)l, 16, 0, 0);
}

#define ASTR 136  // transpose-scratch row stride (shorts)
#define WSTR 132  // old-path W row stride (shorts)

// ---------------- fast-path prep mega-kernel ----------------
// blocks [0,8192): skip->skb | [8192,10240): x->xb | [10240,10348): w2->wt2 transpose
// [10348,10604): w1->wc1 parity-combine | [10604]: zero sums+zb
__global__ __launch_bounds__(256) void hg_prep_k(
    const float* __restrict__ x, const float* __restrict__ skip,
    const float* __restrict__ w1, const float* __restrict__ w2,
    unsigned short* __restrict__ xb, unsigned short* __restrict__ skb,
    unsigned short* __restrict__ wt2, unsigned short* __restrict__ wc1,
    float* __restrict__ sums) {
  __shared__ short T[64 * ASTR];
  int blk = blockIdx.x;
  int tid = threadIdx.x;
  if (blk < 10240) {
    // fp32 -> bf16, 8 elem/thread
    const float* s; unsigned short* d; size_t i;
    if (blk < 8192) { s = skip; d = skb; i = ((size_t)blk * 256 + tid) << 3; }
    else            { s = x;    d = xb;  i = ((size_t)(blk - 8192) * 256 + tid) << 3; }
    float4 a = *(const float4*)(s + i);
    float4 c = *(const float4*)(s + i + 4);
    uint4 o;
    o.x = pk2(a.x, a.y); o.y = pk2(a.z, a.w);
    o.z = pk2(c.x, c.y); o.w = pk2(c.z, c.w);
    *(uint4*)(d + i) = o;
  } else if (blk < 10348) {
    // w2[bt,ci,co] -> wt2[bt,co,ci] bf16
    int bt = blk - 10240;
    const float* src = w2 + (size_t)bt * 8192;
    int co = tid & 63, c0 = tid >> 6;
    for (int i = 0; i < 32; ++i) {
      int ci = c0 + (i << 2);
      T[co * ASTR + ci] = (short)f2b(src[(size_t)ci * 64 + co]);
    }
    __syncthreads();
    unsigned short* dst = wt2 + (size_t)bt * 8192;
    for (int i = 0; i < 4; ++i) {
      int task = tid + (i << 8);
      int row = task >> 4, q = task & 15;
      *(uint4*)(dst + row * 128 + (q << 3)) = *(const uint4*)&T[row * ASTR + (q << 3)];
    }
  } else if (blk < 10604) {
    // parity-combined conv1 weights: wc1[b][dd*16+hh*4+ww][co][ci]
    // S(0,0)={0} S(0,1)={1,2} S(1,0)={0,1} S(1,1)={2}
    int m9 = blk - 10348;
    int b = m9 >> 6, m = m9 & 63;
    int dd = m >> 4, hh = (m >> 2) & 3, ww = m & 3;
    const int ks[4] = {0, 1, 0, 2}, kc[4] = {1, 2, 2, 1};
    int co = tid & 63, c0 = tid >> 6;
    const float* wb = w1 + (size_t)b * 27 * 8192;
    for (int i = 0; i < 32; ++i) {
      int ci = c0 + (i << 2);
      float s = 0.f;
      for (int a = 0; a < kc[dd]; ++a)
        for (int e = 0; e < kc[hh]; ++e)
          for (int c = 0; c < kc[ww]; ++c) {
            int tap = ((ks[dd] + a) * 3 + ks[hh] + e) * 3 + ks[ww] + c;
            s += wb[(size_t)tap * 8192 + (size_t)ci * 64 + co];
          }
      T[co * ASTR + ci] = (short)f2b(s);
    }
    __syncthreads();
    unsigned short* dst = wc1 + (size_t)m9 * 8192;
    for (int i = 0; i < 4; ++i) {
      int task = tid + (i << 8);
      int row = task >> 4, q = task & 15;
      *(uint4*)(dst + row * 128 + (q << 3)) = *(const uint4*)&T[row * ASTR + (q << 3)];
    }
  } else {
    // zero sums (2048 f32) + zb (64 f32, contiguous after sums)
    for (int i = tid; i < 2112; i += 256) sums[i] = 0.f;
  }
}

// ---------------- conv1: parity decomposition over source x ----------------
__global__ __launch_bounds__(256, 3) void hg_c1p_k(
    const unsigned short* __restrict__ xb, const unsigned short* __restrict__ wc1,
    const unsigned short* __restrict__ zb, unsigned short* __restrict__ outb,
    float* __restrict__ sums) {
  __shared__ short Xl[2 * 100 * 128];   // 51200 B: 2 planes x 10x10 cells x 128ch
  int tid = threadIdx.x;
  int xcd = blockIdx.x & 7, slot = blockIdx.x >> 3;   // 1024 blocks
  int b = xcd & 3;
  int t = ((xcd >> 2) << 7) + slot;     // 0..255
  int od = t >> 4, hti = (t >> 2) & 3, wti = t & 3;
  int pd = od & 1, md = od >> 1;
  int lane = tid & 63, quad = lane >> 4, l16 = lane & 15;
  int wid = tid >> 6;
  int ph = wid >> 1, pw = wid & 1;

  for (int pl = 0; pl < 2; ++pl) {
    int sd = md + pd - 1 + pl;
    int dok = ((unsigned)sd < 8u);
    for (int i = 0; i < 7; ++i) {
      int task = tid + (i << 8);
      if (task < 1600) {                // 100 pos x 16 chunks
        int pos = task >> 4, pq = task & 15;
        int q = (pq & 8) | ((pq & 7) ^ (pos & 7));
        int sh = pos / 10, sw = pos - sh * 10;
        int h = (hti << 3) + sh - 1, w = (wti << 3) + sw - 1;
        const unsigned short* src = zb;
        if (dok && (unsigned)h < 32u && (unsigned)w < 32u)
          src = xb + ((((size_t)(b * 8 + sd)) * 32 + h) * 32 + w) * 128 + (q << 3);
        gload16(src, (char*)Xl + ((pl * 1600 + (i << 8) + (tid & 192)) << 4));
      }
    }
  }
  __syncthreads();                      // the ONLY staging barrier

  f32x4 acc[4][4];
#pragma unroll
  for (int i = 0; i < 4; ++i)
#pragma unroll
    for (int j = 0; j < 4; ++j) acc[i][j] = (f32x4){0.f, 0.f, 0.f, 0.f};

  const unsigned short* wcb = wc1 + ((size_t)b * 64 + (pd << 5) + (ph << 3) + (pw << 1)) * 8192;

  for (int td = 0; td < 2; ++td) {
    const char* Xp = (const char*)Xl + td * 25600;
    for (int th = 0; th < 2; ++th) {
      int hb = ph + th;
      for (int tw = 0; tw < 2; ++tw) {
        int wb2 = pw + tw;
        const unsigned short* wp = wcb + (size_t)((td << 4) + (th << 2) + tw) * 8192;
#pragma unroll
        for (int ksx = 0; ksx < 4; ++ksx) {
          int cq = (ksx << 2) + quad;
          short8 av[4], bv[4];
#pragma unroll
          for (int mt = 0; mt < 4; ++mt) {
            int pos = ((mt << 1) + (l16 >> 3) + hb) * 10 + (l16 & 7) + wb2;
            int pc = (cq & 8) | ((cq & 7) ^ (pos & 7));
            av[mt] = *(const short8*)(Xp + pos * 256 + (pc << 4));
          }
#pragma unroll
          for (int nt = 0; nt < 4; ++nt)
            bv[nt] = *(const short8*)(wp + ((nt << 4) + l16) * 128 + (cq << 3));
#pragma unroll
          for (int mt = 0; mt < 4; ++mt)
#pragma unroll
            for (int nt = 0; nt < 4; ++nt)
              acc[mt][nt] = __builtin_amdgcn_mfma_f32_16x16x32_bf16(
                  av[mt], bv[nt], acc[mt][nt], 0, 0, 0);
        }
      }
    }
  }

  __syncthreads();                      // Xl reads done -> stats scratch
  float* sbf = (float*)Xl;
  int rowb = (b * 16 + od) * 64;
#pragma unroll
  for (int nt = 0; nt < 4; ++nt) {
    int n = (nt << 4) + l16;
    float s = 0.f, q2 = 0.f;
#pragma unroll
    for (int mt = 0; mt < 4; ++mt) {
      int mh = (mt << 1) + (quad >> 1);
      int oh = (((hti << 3) + mh) << 1) + ph;
      size_t rb = (size_t)(rowb + oh) * 64;
#pragma unroll
      for (int r = 0; r < 4; ++r) {
        float v = acc[mt][nt][r];
        int ow = (((wti << 3) + ((quad & 1) << 2) + r) << 1) + pw;
        outb[(rb + ow) * 64 + n] = f2b(v);
        s += v; q2 += v * v;
      }
    }
    s += __shfl_xor(s, 16); s += __shfl_xor(s, 32);
    q2 += __shfl_xor(q2, 16); q2 += __shfl_xor(q2, 32);
    if (quad == 0) { sbf[wid * 128 + n] = s; sbf[wid * 128 + 64 + n] = q2; }
  }
  __syncthreads();
  if (tid < 64) {
    float s = sbf[tid] + sbf[128 + tid] + sbf[256 + tid] + sbf[384 + tid];
    float q2 = sbf[64 + tid] + sbf[192 + tid] + sbf[320 + tid] + sbf[448 + tid];
    int sl = (blockIdx.x & 7) << 7;
    atomicAdd(&sums[sl + tid], s);
    atomicAdd(&sums[sl + 64 + tid], q2);
  }
}

// ---------------- conv2: R14 convf (pure-DMA staging) + slotted fused stats ----------
__global__ __launch_bounds__(256) void hg_convf_k(
    const unsigned short* __restrict__ y1n, const unsigned short* __restrict__ skb,
    const unsigned short* __restrict__ wt, const unsigned short* __restrict__ zb,
    float* __restrict__ outf, float* __restrict__ sums) {
  __shared__ short Al[132 * 128];  // 33792 B, unpadded, chunk-swizzled
  __shared__ short Wl[64 * 128];   // 16384 B, unpadded, chunk-swizzled
  int tid = threadIdx.x;
  int xcd = blockIdx.x & 7, slot = blockIdx.x >> 3;
  int b = xcd & 3;
  int t = ((xcd >> 2) << 8) + slot;       // 0..511 tile within sample
  int m0 = (b << 16) + (t << 7);
  int od  = (t >> 5) & 15;
  int oh0 = (t << 1) & 63;
  int lane = tid & 63, quad = lane >> 4, l16 = lane & 15;
  int wm = (tid >> 6) << 5;               // wave row offset 0/32/64/96

  f32x4 acc[2][4];
  for (int i = 0; i < 2; ++i)
    for (int j = 0; j < 4; ++j) acc[i][j] = (f32x4){0.f, 0.f, 0.f, 0.f};

  const unsigned short* wb = wt + (size_t)b * 27 * 8192;

  for (int kd = 0; kd < 3; ++kd) {
    int ud = od + kd - 1;
    int dok = ((unsigned)ud < 16u);
    for (int kh = 0; kh < 3; ++kh) {
      __syncthreads();  // prior MFMAs done before Al/Wl overwrite
      for (int i = 0; i < 9; ++i) {
        int task = tid + (i << 8);
        if (task < 2112) {
          int pos = task >> 4, pq = task & 15;
          int q = (pq & 8) | ((pq & 7) ^ (pos & 7));  // logical chunk (involution)
          int g = (pos >= 66) ? 1 : 0;
          int uw = pos - (g ? 66 : 0) - 1;
          int uh = oh0 + g + kh - 1;
          const unsigned short* src = zb;
          if (dok && (unsigned)uh < 64u && (unsigned)uw < 64u) {
            size_t srow = (((size_t)(b * 16 + ud)) * 64 + uh) * 64 + uw;
            src = (q < 8) ? (y1n + srow * 64 + (q << 3))
                          : (skb + srow * 64 + ((q - 8) << 3));
          }
          gload16(src, (char*)Al + (((i << 8) + (tid & 192)) << 4));
        }
      }
      for (int kw = 0; kw < 3; ++kw) {
        if (kw) __syncthreads();
        int tap = (kd * 3 + kh) * 3 + kw;
        const unsigned short* wsrc = wb + (size_t)tap * 8192;
        {
          int co0 = tid >> 4, pq = tid & 15;
          for (int i = 0; i < 4; ++i) {
            int co = co0 + (i << 4);
            int q = (pq & 8) | ((pq & 7) ^ (co & 7));
            gload16(wsrc + co * 128 + (q << 3),
                    (char*)Wl + (((i << 8) + (tid & 192)) << 4));
          }
        }
        __syncthreads();
        for (int k0 = 0; k0 < 128; k0 += 32) {
          int cq = (k0 >> 3) + quad;
          short8 av[2], bv[4];
          for (int mt = 0; mt < 2; ++mt) {
            int r = wm + (mt << 4) + l16;
            int pos = (r >> 6) * 66 + (r & 63) + kw;
            int pc = (cq & 8) | ((cq & 7) ^ (pos & 7));
            av[mt] = *(const short8*)((const char*)Al + pos * 256 + (pc << 4));
          }
          for (int nt = 0; nt < 4; ++nt) {
            int co = (nt << 4) + l16;
            int pc = (cq & 8) | ((cq & 7) ^ (co & 7));
            bv[nt] = *(const short8*)((const char*)Wl + co * 256 + (pc << 4));
          }
          for (int mt = 0; mt < 2; ++mt)
            for (int nt = 0; nt < 4; ++nt)
              acc[mt][nt] = __builtin_amdgcn_mfma_f32_16x16x32_bf16(
                  av[mt], bv[nt], acc[mt][nt], 0, 0, 0);
        }
      }
    }
  }

  // epilogue + fused stats (cross-wave LDS reduce -> slotted atomics)
  __syncthreads();                      // Al reads done -> scratch
  float* sbf = (float*)Al;
  for (int nt = 0; nt < 4; ++nt) {
    int n = (nt << 4) + l16;
    float s = 0.f, q2 = 0.f;
    for (int mt = 0; mt < 2; ++mt) {
      int mbase = m0 + wm + (mt << 4) + (quad << 2);
      for (int r = 0; r < 4; ++r) {
        float v = acc[mt][nt][r];
        outf[(size_t)(mbase + r) * 64 + n] = v;
        s += v; q2 += v * v;
      }
    }
    s += __shfl_xor(s, 16); s += __shfl_xor(s, 32);
    q2 += __shfl_xor(q2, 16); q2 += __shfl_xor(q2, 32);
    if (quad == 0) { sbf[(wm >> 5) * 128 + n] = s; sbf[(wm >> 5) * 128 + 64 + n] = q2; }
  }
  __syncthreads();
  if (tid < 64) {
    float s = sbf[tid] + sbf[128 + tid] + sbf[256 + tid] + sbf[384 + tid];
    float q2 = sbf[64 + tid] + sbf[192 + tid] + sbf[320 + tid] + sbf[448 + tid];
    int sl = (blockIdx.x & 7) << 7;
    atomicAdd(&sums[sl + tid], s);
    atomicAdd(&sums[sl + 64 + tid], q2);
  }
}

// ---------------- fast-path BN1+ReLU in place on bf16 y1, fin8 folded ----------------
__global__ __launch_bounds__(256) void hg_bnbf_k(unsigned short* __restrict__ y,
                                                 const float* __restrict__ sb,
                                                 const float* __restrict__ gm,
                                                 const float* __restrict__ bt) {
  __shared__ float sc[64], sh[64];
  int tid = threadIdx.x;
  if (tid < 64) {
    float s = 0.f, q2 = 0.f;
    for (int k = 0; k < 8; ++k) { s += sb[(k << 7) + tid]; q2 += sb[(k << 7) + 64 + tid]; }
    float invN = 1.f / 262144.f;
    float mean = s * invN;
    float var  = q2 * invN - mean * mean;
    float scl = gm[tid] * rsqrtf(var + 1e-3f);
    sc[tid] = scl; sh[tid] = bt[tid] - mean * scl;
  }
  __syncthreads();
  size_t i = ((size_t)blockIdx.x * 256 + tid) << 3;
  int c0 = (int)(i & 63);
  uint4 v = *(uint4*)(y + i);
  unsigned int u[4] = {v.x, v.y, v.z, v.w};
  for (int q = 0; q < 4; ++q) {
    int c = c0 + q * 2;
    float f0 = sc[c] * bf2f((unsigned short)(u[q] & 0xFFFFu)) + sh[c];
    float f1 = sc[c + 1] * bf2f((unsigned short)(u[q] >> 16)) + sh[c + 1];
    u[q] = pk2(f0 > 0.f ? f0 : 0.f, f1 > 0.f ? f1 : 0.f);
  }
  *(uint4*)(y + i) = make_uint4(u[0], u[1], u[2], u[3]);
}

// ---------------- fast-path BN2+ReLU on fp32 out, fin8 folded ----------------
__global__ __launch_bounds__(256) void hg_bnrf_k(float* __restrict__ y,
                                                 const float* __restrict__ sb,
                                                 const float* __restrict__ gm,
                                                 const float* __restrict__ bt) {
  __shared__ float sc[64], sh[64];
  int tid = threadIdx.x;
  if (tid < 64) {
    float s = 0.f, q2 = 0.f;
    for (int k = 0; k < 8; ++k) { s += sb[(k << 7) + tid]; q2 += sb[(k << 7) + 64 + tid]; }
    float invN = 1.f / 262144.f;
    float mean = s * invN;
    float var  = q2 * invN - mean * mean;
    float scl = gm[tid] * rsqrtf(var + 1e-3f);
    sc[tid] = scl; sh[tid] = bt[tid] - mean * scl;
  }
  __syncthreads();
  size_t i = (size_t)blockIdx.x * 256 + tid;  // float4 index
  int c4 = ((int)i & 15) << 2;
  float4 v = *(float4*)(y + i * 4);
  float f;
  f = sc[c4]     * v.x + sh[c4];     v.x = f > 0.f ? f : 0.f;
  f = sc[c4 + 1] * v.y + sh[c4 + 1]; v.y = f > 0.f ? f : 0.f;
  f = sc[c4 + 2] * v.z + sh[c4 + 2]; v.z = f > 0.f ? f : 0.f;
  f = sc[c4 + 3] * v.w + sh[c4 + 3]; v.w = f > 0.f ? f : 0.f;
  *(float4*)(y + i * 4) = v;
}

// ================= fallback path (unchanged, ws too small) =================
__global__ __launch_bounds__(256) void hg_wt_k(const float* __restrict__ w1,
                                               const float* __restrict__ w2,
                                               unsigned short* __restrict__ wt1,
                                               unsigned short* __restrict__ wt2) {
  __shared__ short T[64 * ASTR];
  int blk = blockIdx.x;
  int sel = blk >= 108;
  const float* w = sel ? w2 : w1;
  unsigned short* wt = sel ? wt2 : wt1;
  int bt = sel ? blk - 108 : blk;
  const float* src = w + (size_t)bt * 8192;
  int tid = threadIdx.x;
  int co = tid & 63;
  int c0 = tid >> 6;
  for (int i = 0; i < 32; ++i) {
    int ci = c0 + (i << 2);
    T[co * ASTR + ci] = (short)f2b(src[(size_t)ci * 64 + co]);
  }
  __syncthreads();
  unsigned short* dst = wt + (size_t)bt * 8192;
  for (int i = 0; i < 4; ++i) {
    int task = tid + (i << 8);
    int row = task >> 4, q = task & 15;
    *(uint4*)(dst + row * 128 + (q << 3)) = *(const uint4*)&T[row * ASTR + (q << 3)];
  }
}

__global__ __launch_bounds__(256) void hg_conv_o_k(
    const float* __restrict__ xf, const unsigned short* __restrict__ y1n,
    const float* __restrict__ skip, const float* __restrict__ wf,
    const unsigned short* __restrict__ wt, const float* __restrict__ bn,
    unsigned short* __restrict__ outb, float* __restrict__ outf,
    int mode, int has_wt) {
  __shared__ short Al[132 * ASTR];
  __shared__ short Wl[64 * WSTR];
  __shared__ float sbl[128];
  int tid = threadIdx.x;
  int xcd = blockIdx.x & 7, slot = blockIdx.x >> 3;
  int b = xcd & 3;
  int t = ((xcd >> 2) << 8) + slot;
  int m0 = (b << 16) + (t << 7);
  int od  = (t >> 5) & 15;
  int oh0 = (t << 1) & 63;
  int lane = tid & 63, quad = lane >> 4, l16 = lane & 15;
  int wm = (tid >> 6) << 5;

  if (mode == 1 && tid < 128) sbl[tid] = bn[tid];

  f32x4 acc[2][4];
  for (int i = 0; i < 2; ++i)
    for (int j = 0; j < 4; ++j) acc[i][j] = (f32x4){0.f, 0.f, 0.f, 0.f};

  const float* wbf = wf + (size_t)b * 27 * 8192;
  const unsigned short* wbt = wt + (size_t)b * 27 * 8192;

  for (int kd = 0; kd < 3; ++kd) {
    int ud = od + kd - 1;
    int dok = (ud >= 0 && ud < 16);
    for (int kh = 0; kh < 3; ++kh) {
      __syncthreads();
      for (int i = 0; i < 9; ++i) {
        int task = tid + (i << 8);
        if (task < 2112) {
          int chunk = task & 15;
          int pos = task >> 4;
          int g = (pos >= 66) ? 1 : 0;
          int uwi = pos - (g ? 66 : 0);
          int uh = oh0 + g + kh - 1;
          int uw = uwi - 1;
          uint4 val = make_uint4(0u, 0u, 0u, 0u);
          if (dok && (unsigned)uh < 64u && (unsigned)uw < 64u) {
            if (mode == 0) {
              size_t src = ((((size_t)(b * 8 + (ud >> 1))) * 32 + (uh >> 1)) * 32 +
                            (uw >> 1)) * 128 + (chunk << 3);
              float4 f0 = *(const float4*)(xf + src);
              float4 f1 = *(const float4*)(xf + src + 4);
              val.x = pk2(f0.x, f0.y); val.y = pk2(f0.z, f0.w);
              val.z = pk2(f1.x, f1.y); val.w = pk2(f1.z, f1.w);
            } else {
              size_t srow = (((size_t)(b * 16 + ud)) * 64 + uh) * 64 + uw;
              if (chunk < 8) {
                uint4 raw = *(const uint4*)(y1n + srow * 64 + (chunk << 3));
                unsigned int u[4] = {raw.x, raw.y, raw.z, raw.w};
                unsigned int o[4];
                int c0 = chunk << 3;
                for (int q = 0; q < 4; ++q) {
                  int c = c0 + q * 2;
                  float f0 = sbl[c] * bf2f((unsigned short)(u[q] & 0xFFFFu)) + sbl[64 + c];
                  float f1 = sbl[c + 1] * bf2f((unsigned short)(u[q] >> 16)) + sbl[64 + c + 1];
                  o[q] = pk2(f0 > 0.f ? f0 : 0.f, f1 > 0.f ? f1 : 0.f);
                }
                val = make_uint4(o[0], o[1], o[2], o[3]);
              } else {
                const float* sp = skip + srow * 64 + ((chunk - 8) << 3);
                float4 f0 = *(const float4*)(sp);
                float4 f1 = *(const float4*)(sp + 4);
                val.x = pk2(f0.x, f0.y); val.y = pk2(f0.z, f0.w);
                val.z = pk2(f1.x, f1.y); val.w = pk2(f1.z, f1.w);
              }
            }
          }
          *(uint4*)&Al[pos * ASTR + (chunk << 3)] = val;
        }
      }
      for (int kw = 0; kw < 3; ++kw) {
        if (kw) __syncthreads();
        int tap = (kd * 3 + kh) * 3 + kw;
        if (has_wt) {
          const unsigned short* wsrc = wbt + (size_t)tap * 8192;
          for (int i = 0; i < 4; ++i) {
            int task = tid + (i << 8);
            int co = task >> 4, q = task & 15;
            *(uint4*)&Wl[co * WSTR + (q << 3)] = *(const uint4*)(wsrc + co * 128 + (q << 3));
          }
        } else {
          const float* wp = wbf + (size_t)tap * 8192 + (tid & 63);
          int wco = tid & 63;
          int ci0 = (tid >> 6) << 5;
          for (int c = 0; c < 32; c += 2) {
            float f0 = wp[(size_t)(ci0 + c) * 64];
            float f1 = wp[(size_t)(ci0 + c + 1) * 64];
            *(unsigned int*)&Wl[wco * WSTR + ci0 + c] = pk2(f0, f1);
          }
        }
        __syncthreads();
        for (int k0 = 0; k0 < 128; k0 += 32) {
          int kk = k0 + (quad << 3);
          union { uint4 u; short8 s; } cv;
          short8 av[2];
          for (int mt = 0; mt < 2; ++mt) {
            int r = wm + (mt << 4) + l16;
            int g = r >> 6, ow = r & 63;
            cv.u = *(const uint4*)&Al[(g * 66 + ow + kw) * ASTR + kk];
            av[mt] = cv.s;
          }
          short8 bv[4];
          for (int nt = 0; nt < 4; ++nt) {
            int base = ((nt << 4) + l16) * WSTR + kk;
            uint2 lo = *(const uint2*)&Wl[base];
            uint2 hi = *(const uint2*)&Wl[base + 4];
            cv.u = make_uint4(lo.x, lo.y, hi.x, hi.y);
            bv[nt] = cv.s;
          }
          for (int mt = 0; mt < 2; ++mt)
            for (int nt = 0; nt < 4; ++nt)
              acc[mt][nt] = __builtin_amdgcn_mfma_f32_16x16x32_bf16(
                  av[mt], bv[nt], acc[mt][nt], 0, 0, 0);
        }
      }
    }
  }

  for (int mt = 0; mt < 2; ++mt) {
    int mbase = m0 + wm + (mt << 4) + (quad << 2);
    for (int nt = 0; nt < 4; ++nt) {
      int n = (nt << 4) + l16;
      for (int r = 0; r < 4; ++r) {
        float v = acc[mt][nt][r];
        size_t o = (size_t)(mbase + r) * 64 + n;
        if (mode == 0) outb[o] = f2b(v);
        else outf[o] = v;
      }
    }
  }
}

__global__ void hg_zero_k(float* __restrict__ p, int n) {
  for (int i = threadIdx.x; i < n; i += 256) p[i] = 0.f;
}

__global__ __launch_bounds__(256) void hg_stats_k(const unsigned short* __restrict__ yb,
                                                  const float* __restrict__ yf, int isf,
                                                  float* __restrict__ sums) {
  int t = threadIdx.x;
  int c = t & 63;
  int r0 = blockIdx.x * 4 + (t >> 6);
  float sum = 0.f, ss = 0.f;
  for (int r = r0; r < 262144; r += 4096) {
    size_t idx = (size_t)r * 64 + c;
    float v = isf ? yf[idx] : bf2f(yb[idx]);
    sum += v; ss += v * v;
  }
  atomicAdd(&sums[c], sum);
  atomicAdd(&sums[64 + c], ss);
}

__global__ void hg_fin_k(float* __restrict__ sb, const float* __restrict__ gm,
                         const float* __restrict__ bt) {
  int c = threadIdx.x;  // 64
  float invN = 1.f / 262144.f;
  float mean = sb[c] * invN;
  float var  = sb[64 + c] * invN - mean * mean;
  float sc = gm[c] * rsqrtf(var + 1e-3f);
  sb[c] = sc;
  sb[64 + c] = bt[c] - mean * sc;
}

__global__ __launch_bounds__(256) void hg_bnb_k(unsigned short* __restrict__ y,
                                                const float* __restrict__ sb) {
  size_t i = ((size_t)blockIdx.x * 256 + threadIdx.x) << 3;
  int c0 = (int)(i & 63);
  uint4 v = *(uint4*)(y + i);
  unsigned int u[4] = {v.x, v.y, v.z, v.w};
  for (int q = 0; q < 4; ++q) {
    int c = c0 + q * 2;
    float f0 = sb[c] * bf2f((unsigned short)(u[q] & 0xFFFFu)) + sb[64 + c];
    float f1 = sb[c + 1] * bf2f((unsigned short)(u[q] >> 16)) + sb[64 + c + 1];
    u[q] = pk2(f0 > 0.f ? f0 : 0.f, f1 > 0.f ? f1 : 0.f);
  }
  *(uint4*)(y + i) = make_uint4(u[0], u[1], u[2], u[3]);
}

__global__ __launch_bounds__(256) void hg_bnrelu_f_k(float* __restrict__ y,
                                                     const float* __restrict__ sb) {
  size_t i = (size_t)blockIdx.x * 256 + threadIdx.x;  // float4 index
  int c4 = ((int)i & 15) << 2;
  float4 v = *(float4*)(y + i * 4);
  float f;
  f = sb[c4]     * v.x + sb[64 + c4];     v.x = f > 0.f ? f : 0.f;
  f = sb[c4 + 1] * v.y + sb[64 + c4 + 1]; v.y = f > 0.f ? f : 0.f;
  f = sb[c4 + 2] * v.z + sb[64 + c4 + 2]; v.z = f > 0.f ? f : 0.f;
  f = sb[c4 + 3] * v.w + sb[64 + c4 + 3]; v.w = f > 0.f ? f : 0.f;
  *(float4*)(y + i * 4) = v;
}

extern "C" void kernel_launch(void* const* d_in, const int* in_sizes, int n_in,
                              void* d_out, int out_size, void* d_ws, size_t ws_size,
                              hipStream_t stream) {
  (void)out_size;
  int ix = 0, iw1 = 1, iw2 = 2, isk = 3, ig1 = 4, ib1 = 5, ig2 = 6, ib2 = 7;
  if (n_in >= 9 && in_sizes[0] == 4194304 && in_sizes[1] == 884736 &&
      in_sizes[3] == 16777216 && in_sizes[4] == 64) {
    // insertion order
  } else if (n_in >= 9 && in_sizes[0] == 64 && in_sizes[4] == 16777216 &&
             in_sizes[6] == 884736 && in_sizes[8] == 4194304) {
    ib1 = 0; ib2 = 1; ig1 = 2; ig2 = 3; isk = 4; iw1 = 6; iw2 = 7; ix = 8;
  } else {
    return;
  }
  if (ws_size < (32ull << 20) + 2048ull) return;

  const float* x    = (const float*)d_in[ix];
  const float* w1   = (const float*)d_in[iw1];
  const float* w2   = (const float*)d_in[iw2];
  const float* skip = (const float*)d_in[isk];
  const float* g1   = (const float*)d_in[ig1];
  const float* b1   = (const float*)d_in[ib1];
  const float* g2   = (const float*)d_in[ig2];
  const float* b2   = (const float*)d_in[ib2];
  float* out = (float*)d_out;

  // fast-path layout
  const size_t OFF_SUMS = 32ull << 20;            // 8 KiB: 2 layers x 8 slots x 128 f32
  const size_t OFF_ZB   = OFF_SUMS + 8192;        // zero16 region (256 B)
  const size_t OFF_WT2  = OFF_ZB + 256;           // wt2 transposed
  const size_t OFF_XB   = OFF_WT2 + 2ull * 1769472;
  const size_t OFF_SKB  = OFF_XB + 8388608;       // 4194304 bf16
  const size_t OFF_WC1  = OFF_SKB + 33554432;     // 16777216 bf16
  const size_t NEED     = OFF_WC1 + 4194304;      // ~79.4 MB

  unsigned short* y1 = (unsigned short*)d_ws;     // 32 MiB bf16

  if (ws_size >= NEED) {
    // -------- fast path: 5 dispatches --------
    float* sums  = (float*)((char*)d_ws + OFF_SUMS);
    float* sums1 = sums;                          // 8 slots x 128
    float* sums2 = sums + 1024;                   // 8 slots x 128
    unsigned short* zb  = (unsigned short*)((char*)d_ws + OFF_ZB);
    unsigned short* wt2 = (unsigned short*)((char*)d_ws + OFF_WT2);
    unsigned short* xb  = (unsigned short*)((char*)d_ws + OFF_XB);
    unsigned short* skb = (unsigned short*)((char*)d_ws + OFF_SKB);
    unsigned short* wc1 = (unsigned short*)((char*)d_ws + OFF_WC1);

    hg_prep_k<<<10605, 256, 0, stream>>>(x, skip, w1, w2, xb, skb, wt2, wc1, sums);
    hg_c1p_k<<<1024, 256, 0, stream>>>(xb, wc1, zb, y1, sums1);
    hg_bnbf_k<<<8192, 256, 0, stream>>>(y1, sums1, g1, b1);
    hg_convf_k<<<2048, 256, 0, stream>>>(y1, skb, wt2, zb, out, sums2);
    hg_bnrf_k<<<16384, 256, 0, stream>>>(out, sums2, g2, b2);
  } else {
    // -------- fallback: R9 path (original layout) --------
    float* sums  = (float*)((char*)d_ws + (32ull << 20));
    float* sums1 = sums;
    float* sums2 = sums + 128;
    unsigned short* wt1 = (unsigned short*)((char*)d_ws + (32ull << 20) + 2048ull);
    unsigned short* wt2 = wt1 + 884736ull;
    const size_t WS_NEED = (32ull << 20) + 2048ull + 2ull * 884736ull * 2ull;
    int has_wt = (ws_size >= WS_NEED) ? 1 : 0;

    hg_zero_k<<<1, 256, 0, stream>>>(sums, 512);
    if (has_wt) hg_wt_k<<<216, 256, 0, stream>>>(w1, w2, wt1, wt2);
    hg_conv_o_k<<<2048, 256, 0, stream>>>(x, y1, skip, w1, wt1, sums1, y1, out, 0, has_wt);
    hg_stats_k<<<1024, 256, 0, stream>>>(y1, out, 0, sums1);
    hg_fin_k<<<1, 64, 0, stream>>>(sums1, g1, b1);
    hg_conv_o_k<<<2048, 256, 0, stream>>>(x, y1, skip, w2, wt2, sums1, y1, out, 1, has_wt);
    hg_stats_k<<<1024, 256, 0, stream>>>(y1, out, 1, sums2);
    hg_fin_k<<<1, 64, 0, stream>>>(sums2, g2, b2);
    hg_bnrelu_f_k<<<16384, 256, 0, stream>>>(out, sums2);
  }
}

// Round 9
// 422.793 us; speedup vs baseline: 1.2406x; 1.0016x over previous
//
#include <hip/hip_runtime.h>

// HyperGANUpBlock (all fp32 I/O): x[4,8,32,32,128] -> up2 -> conv3^3(128->64, per-sample
// w1) -> BN(train,1e-3)+ReLU -> concat skip -> conv3^3(128->64, per-sample w2) -> BN+ReLU.
// R18: conv2 switched to mfma_f32_32x32x16_bf16 with 2x2 32-tiles/wave (wave tile 64x64)
// -> LDS reads 96->64 b128/block-tap (1.5x) at IDENTICAL slab/occupancy (50176B, 3
// blk/CU). 4 waves = (row-half x k-half); k-halves combined via 32KB conflict-free LDS
// interchange. A/B frag: row=lane&31, k=(lane>>5)*8+e (generalizes verified 16x16x32);
// C/D: col=lane&31, row=(reg&3)+8*(reg>>2)+4*(lane>>5) (HW-verified m74/m101).
// Rest = R17: 5 dispatches, parity conv1, fused prep, fin8 folded into BN consumers.
// ws(fast): y1 32Mi | sums 8Ki | zb 256B | wt2 1.7Mi | (spare) | xb | skb | wc1.

typedef __attribute__((ext_vector_type(8))) short short8;
typedef __attribute__((ext_vector_type(4))) float f32x4;
typedef __attribute__((ext_vector_type(16))) float f32x16;

__device__ __forceinline__ float bf2f(unsigned short u) {
  union { unsigned int i; float f; } v; v.i = ((unsigned int)u) << 16; return v.f;
}
__device__ __forceinline__ unsigned short f2b(float f) {
  union { float ff; unsigned int u; } v; v.ff = f;
  unsigned int x = v.u;
  return (unsigned short)((x + 0x7FFFu + ((x >> 16) & 1u)) >> 16);  // RNE
}
__device__ __forceinline__ unsigned int pk2(float a, float b) {
  return (unsigned int)f2b(a) | ((unsigned int)f2b(b) << 16);
}
__device__ __forceinline__ void gload16(const void* g, void* l) {
  __builtin_amdgcn_global_load_lds(
      (const __attribute__((address_space(1))) void*)g,
      (__attribute__((address_space(3))) void*)l, 16, 0, 0);
}

#define ASTR 136  // transpose-scratch row stride (shorts)
#define WSTR 132  // old-path W row stride (shorts)

// ---------------- fast-path prep mega-kernel ----------------
// blocks [0,8192): skip->skb | [8192,10240): x->xb | [10240,10348): w2->wt2 transpose
// [10348,10604): w1->wc1 parity-combine | [10604]: zero sums+zb
__global__ __launch_bounds__(256) void hg_prep_k(
    const float* __restrict__ x, const float* __restrict__ skip,
    const float* __restrict__ w1, const float* __restrict__ w2,
    unsigned short* __restrict__ xb, unsigned short* __restrict__ skb,
    unsigned short* __restrict__ wt2, unsigned short* __restrict__ wc1,
    float* __restrict__ sums) {
  __shared__ short T[64 * ASTR];
  int blk = blockIdx.x;
  int tid = threadIdx.x;
  if (blk < 10240) {
    // fp32 -> bf16, 8 elem/thread
    const float* s; unsigned short* d; size_t i;
    if (blk < 8192) { s = skip; d = skb; i = ((size_t)blk * 256 + tid) << 3; }
    else            { s = x;    d = xb;  i = ((size_t)(blk - 8192) * 256 + tid) << 3; }
    float4 a = *(const float4*)(s + i);
    float4 c = *(const float4*)(s + i + 4);
    uint4 o;
    o.x = pk2(a.x, a.y); o.y = pk2(a.z, a.w);
    o.z = pk2(c.x, c.y); o.w = pk2(c.z, c.w);
    *(uint4*)(d + i) = o;
  } else if (blk < 10348) {
    // w2[bt,ci,co] -> wt2[bt,co,ci] bf16
    int bt = blk - 10240;
    const float* src = w2 + (size_t)bt * 8192;
    int co = tid & 63, c0 = tid >> 6;
    for (int i = 0; i < 32; ++i) {
      int ci = c0 + (i << 2);
      T[co * ASTR + ci] = (short)f2b(src[(size_t)ci * 64 + co]);
    }
    __syncthreads();
    unsigned short* dst = wt2 + (size_t)bt * 8192;
    for (int i = 0; i < 4; ++i) {
      int task = tid + (i << 8);
      int row = task >> 4, q = task & 15;
      *(uint4*)(dst + row * 128 + (q << 3)) = *(const uint4*)&T[row * ASTR + (q << 3)];
    }
  } else if (blk < 10604) {
    // parity-combined conv1 weights: wc1[b][dd*16+hh*4+ww][co][ci]
    // S(0,0)={0} S(0,1)={1,2} S(1,0)={0,1} S(1,1)={2}
    int m9 = blk - 10348;
    int b = m9 >> 6, m = m9 & 63;
    int dd = m >> 4, hh = (m >> 2) & 3, ww = m & 3;
    const int ks[4] = {0, 1, 0, 2}, kc[4] = {1, 2, 2, 1};
    int co = tid & 63, c0 = tid >> 6;
    const float* wb = w1 + (size_t)b * 27 * 8192;
    for (int i = 0; i < 32; ++i) {
      int ci = c0 + (i << 2);
      float s = 0.f;
      for (int a = 0; a < kc[dd]; ++a)
        for (int e = 0; e < kc[hh]; ++e)
          for (int c = 0; c < kc[ww]; ++c) {
            int tap = ((ks[dd] + a) * 3 + ks[hh] + e) * 3 + ks[ww] + c;
            s += wb[(size_t)tap * 8192 + (size_t)ci * 64 + co];
          }
      T[co * ASTR + ci] = (short)f2b(s);
    }
    __syncthreads();
    unsigned short* dst = wc1 + (size_t)m9 * 8192;
    for (int i = 0; i < 4; ++i) {
      int task = tid + (i << 8);
      int row = task >> 4, q = task & 15;
      *(uint4*)(dst + row * 128 + (q << 3)) = *(const uint4*)&T[row * ASTR + (q << 3)];
    }
  } else {
    // zero sums (2048 f32) + zb (64 f32, contiguous after sums)
    for (int i = tid; i < 2112; i += 256) sums[i] = 0.f;
  }
}

// ---------------- conv1: parity decomposition over source x ----------------
__global__ __launch_bounds__(256, 3) void hg_c1p_k(
    const unsigned short* __restrict__ xb, const unsigned short* __restrict__ wc1,
    const unsigned short* __restrict__ zb, unsigned short* __restrict__ outb,
    float* __restrict__ sums) {
  __shared__ short Xl[2 * 100 * 128];   // 51200 B: 2 planes x 10x10 cells x 128ch
  int tid = threadIdx.x;
  int xcd = blockIdx.x & 7, slot = blockIdx.x >> 3;   // 1024 blocks
  int b = xcd & 3;
  int t = ((xcd >> 2) << 7) + slot;     // 0..255
  int od = t >> 4, hti = (t >> 2) & 3, wti = t & 3;
  int pd = od & 1, md = od >> 1;
  int lane = tid & 63, quad = lane >> 4, l16 = lane & 15;
  int wid = tid >> 6;
  int ph = wid >> 1, pw = wid & 1;

  for (int pl = 0; pl < 2; ++pl) {
    int sd = md + pd - 1 + pl;
    int dok = ((unsigned)sd < 8u);
    for (int i = 0; i < 7; ++i) {
      int task = tid + (i << 8);
      if (task < 1600) {                // 100 pos x 16 chunks
        int pos = task >> 4, pq = task & 15;
        int q = (pq & 8) | ((pq & 7) ^ (pos & 7));
        int sh = pos / 10, sw = pos - sh * 10;
        int h = (hti << 3) + sh - 1, w = (wti << 3) + sw - 1;
        const unsigned short* src = zb;
        if (dok && (unsigned)h < 32u && (unsigned)w < 32u)
          src = xb + ((((size_t)(b * 8 + sd)) * 32 + h) * 32 + w) * 128 + (q << 3);
        gload16(src, (char*)Xl + ((pl * 1600 + (i << 8) + (tid & 192)) << 4));
      }
    }
  }
  __syncthreads();                      // the ONLY staging barrier

  f32x4 acc[4][4];
#pragma unroll
  for (int i = 0; i < 4; ++i)
#pragma unroll
    for (int j = 0; j < 4; ++j) acc[i][j] = (f32x4){0.f, 0.f, 0.f, 0.f};

  const unsigned short* wcb = wc1 + ((size_t)b * 64 + (pd << 5) + (ph << 3) + (pw << 1)) * 8192;

  for (int td = 0; td < 2; ++td) {
    const char* Xp = (const char*)Xl + td * 25600;
    for (int th = 0; th < 2; ++th) {
      int hb = ph + th;
      for (int tw = 0; tw < 2; ++tw) {
        int wb2 = pw + tw;
        const unsigned short* wp = wcb + (size_t)((td << 4) + (th << 2) + tw) * 8192;
#pragma unroll
        for (int ksx = 0; ksx < 4; ++ksx) {
          int cq = (ksx << 2) + quad;
          short8 av[4], bv[4];
#pragma unroll
          for (int mt = 0; mt < 4; ++mt) {
            int pos = ((mt << 1) + (l16 >> 3) + hb) * 10 + (l16 & 7) + wb2;
            int pc = (cq & 8) | ((cq & 7) ^ (pos & 7));
            av[mt] = *(const short8*)(Xp + pos * 256 + (pc << 4));
          }
#pragma unroll
          for (int nt = 0; nt < 4; ++nt)
            bv[nt] = *(const short8*)(wp + ((nt << 4) + l16) * 128 + (cq << 3));
#pragma unroll
          for (int mt = 0; mt < 4; ++mt)
#pragma unroll
            for (int nt = 0; nt < 4; ++nt)
              acc[mt][nt] = __builtin_amdgcn_mfma_f32_16x16x32_bf16(
                  av[mt], bv[nt], acc[mt][nt], 0, 0, 0);
        }
      }
    }
  }

  __syncthreads();                      // Xl reads done -> stats scratch
  float* sbf = (float*)Xl;
  int rowb = (b * 16 + od) * 64;
#pragma unroll
  for (int nt = 0; nt < 4; ++nt) {
    int n = (nt << 4) + l16;
    float s = 0.f, q2 = 0.f;
#pragma unroll
    for (int mt = 0; mt < 4; ++mt) {
      int mh = (mt << 1) + (quad >> 1);
      int oh = (((hti << 3) + mh) << 1) + ph;
      size_t rb = (size_t)(rowb + oh) * 64;
#pragma unroll
      for (int r = 0; r < 4; ++r) {
        float v = acc[mt][nt][r];
        int ow = (((wti << 3) + ((quad & 1) << 2) + r) << 1) + pw;
        outb[(rb + ow) * 64 + n] = f2b(v);
        s += v; q2 += v * v;
      }
    }
    s += __shfl_xor(s, 16); s += __shfl_xor(s, 32);
    q2 += __shfl_xor(q2, 16); q2 += __shfl_xor(q2, 32);
    if (quad == 0) { sbf[wid * 128 + n] = s; sbf[wid * 128 + 64 + n] = q2; }
  }
  __syncthreads();
  if (tid < 64) {
    float s = sbf[tid] + sbf[128 + tid] + sbf[256 + tid] + sbf[384 + tid];
    float q2 = sbf[64 + tid] + sbf[192 + tid] + sbf[320 + tid] + sbf[448 + tid];
    int sl = (blockIdx.x & 7) << 7;
    atomicAdd(&sums[sl + tid], s);
    atomicAdd(&sums[sl + 64 + tid], q2);
  }
}

// ---------------- conv2: 32x32x16 MFMA, (row-half x k-half) waves ----------------
__global__ __launch_bounds__(256) void hg_convf_k(
    const unsigned short* __restrict__ y1n, const unsigned short* __restrict__ skb,
    const unsigned short* __restrict__ wt, const unsigned short* __restrict__ zb,
    float* __restrict__ outf, float* __restrict__ sums) {
  __shared__ short Al[132 * 128];  // 33792 B, unpadded, chunk-swizzled
  __shared__ short Wl[64 * 128];   // 16384 B, unpadded, chunk-swizzled
  int tid = threadIdx.x;
  int xcd = blockIdx.x & 7, slot = blockIdx.x >> 3;
  int b = xcd & 3;
  int t = ((xcd >> 2) << 8) + slot;       // 0..511 tile within sample
  int m0 = (b << 16) + (t << 7);
  int od  = (t >> 5) & 15;
  int oh0 = (t << 1) & 63;
  int lane = tid & 63, l32 = lane & 31, lh = lane >> 5;
  int wid = tid >> 6;
  int wh = wid & 1;                   // row half: rows wh*64 .. +63
  int ks = wid >> 1;                  // k half: chunks ks*8 .. +7

  f32x16 acc[2][2];
#pragma unroll
  for (int e = 0; e < 16; ++e) {
    acc[0][0][e] = 0.f; acc[0][1][e] = 0.f; acc[1][0][e] = 0.f; acc[1][1][e] = 0.f;
  }

  const unsigned short* wb = wt + (size_t)b * 27 * 8192;

  for (int kd = 0; kd < 3; ++kd) {
    int ud = od + kd - 1;
    int dok = ((unsigned)ud < 16u);
    for (int kh = 0; kh < 3; ++kh) {
      __syncthreads();  // prior MFMAs done before Al/Wl overwrite
      for (int i = 0; i < 9; ++i) {
        int task = tid + (i << 8);
        if (task < 2112) {
          int pos = task >> 4, pq = task & 15;
          int q = (pq & 8) | ((pq & 7) ^ (pos & 7));  // logical chunk (involution)
          int g = (pos >= 66) ? 1 : 0;
          int uw = pos - (g ? 66 : 0) - 1;
          int uh = oh0 + g + kh - 1;
          const unsigned short* src = zb;
          if (dok && (unsigned)uh < 64u && (unsigned)uw < 64u) {
            size_t srow = (((size_t)(b * 16 + ud)) * 64 + uh) * 64 + uw;
            src = (q < 8) ? (y1n + srow * 64 + (q << 3))
                          : (skb + srow * 64 + ((q - 8) << 3));
          }
          gload16(src, (char*)Al + (((i << 8) + (tid & 192)) << 4));
        }
      }
      for (int kw = 0; kw < 3; ++kw) {
        if (kw) __syncthreads();
        int tap = (kd * 3 + kh) * 3 + kw;
        const unsigned short* wsrc = wb + (size_t)tap * 8192;
        {
          int co0 = tid >> 4, pq = tid & 15;
          for (int i = 0; i < 4; ++i) {
            int co = co0 + (i << 4);
            int q = (pq & 8) | ((pq & 7) ^ (co & 7));
            gload16(wsrc + co * 128 + (q << 3),
                    (char*)Wl + (((i << 8) + (tid & 192)) << 4));
          }
        }
        __syncthreads();
        // 4 K=16 steps x (2 m x 2 n) 32-tiles
#pragma unroll
        for (int kt = 0; kt < 4; ++kt) {
          int ch = (ks << 3) + (kt << 1) + lh;   // logical chunk 0..15
          short8 av[2], bv[2];
#pragma unroll
          for (int mt = 0; mt < 2; ++mt) {
            int r = (wh << 6) + (mt << 5) + l32;
            int pos = (r >> 6) * 66 + (r & 63) + kw;
            int pc = (ch & 8) | ((ch & 7) ^ (pos & 7));
            av[mt] = *(const short8*)((const char*)Al + pos * 256 + (pc << 4));
          }
#pragma unroll
          for (int nt = 0; nt < 2; ++nt) {
            int co = (nt << 5) + l32;
            int pc = (ch & 8) | ((ch & 7) ^ (co & 7));
            bv[nt] = *(const short8*)((const char*)Wl + co * 256 + (pc << 4));
          }
#pragma unroll
          for (int mt = 0; mt < 2; ++mt)
#pragma unroll
            for (int nt = 0; nt < 2; ++nt)
              acc[mt][nt] = __builtin_amdgcn_mfma_f32_32x32x16_bf16(
                  av[mt], bv[nt], acc[mt][nt], 0, 0, 0);
        }
      }
    }
  }

  // ---- k-half combine: ks=1 dump to Al (16 pieces x 128 slots x 16B, conflict-free) ----
  __syncthreads();                      // all MFMAs / Al reads done
  if (ks == 1) {
    char* base = (char*)Al + (((wh << 6) + lane) << 4);
#pragma unroll
    for (int mt = 0; mt < 2; ++mt)
#pragma unroll
      for (int nt = 0; nt < 2; ++nt)
#pragma unroll
        for (int r4 = 0; r4 < 4; ++r4) {
          f32x4 v = {acc[mt][nt][(r4 << 2)], acc[mt][nt][(r4 << 2) + 1],
                     acc[mt][nt][(r4 << 2) + 2], acc[mt][nt][(r4 << 2) + 3]};
          *(f32x4*)(base + ((((mt << 1) + nt) << 2) + r4) * 2048) = v;
        }
  }
  __syncthreads();
  float* sbf = (float*)Wl;              // stats scratch (disjoint from Al)
  if (ks == 0) {
    const char* base = (const char*)Al + (((wh << 6) + lane) << 4);
#pragma unroll
    for (int mt = 0; mt < 2; ++mt)
#pragma unroll
      for (int nt = 0; nt < 2; ++nt)
#pragma unroll
        for (int r4 = 0; r4 < 4; ++r4) {
          f32x4 v = *(const f32x4*)(base + ((((mt << 1) + nt) << 2) + r4) * 2048);
#pragma unroll
          for (int j = 0; j < 4; ++j) acc[mt][nt][(r4 << 2) + j] += v[j];
        }
    // write + stats. C/D: col = lane&31, row = (reg&3) + 8*(reg>>2) + 4*lh
#pragma unroll
    for (int nt = 0; nt < 2; ++nt) {
      int n = (nt << 5) + l32;
      float s = 0.f, q2 = 0.f;
#pragma unroll
      for (int mt = 0; mt < 2; ++mt) {
        int rbase = m0 + (wh << 6) + (mt << 5) + (lh << 2);
#pragma unroll
        for (int r = 0; r < 16; ++r) {
          float v = acc[mt][nt][r];
          int row = rbase + (r & 3) + ((r >> 2) << 3);
          outf[(size_t)row * 64 + n] = v;
          s += v; q2 += v * v;
        }
      }
      s += __shfl_xor(s, 32);
      q2 += __shfl_xor(q2, 32);
      if (lh == 0) { sbf[(wh << 7) + n] = s; sbf[(wh << 7) + 64 + n] = q2; }
    }
  }
  __syncthreads();
  if (tid < 64) {
    float s = sbf[tid] + sbf[128 + tid];
    float q2 = sbf[64 + tid] + sbf[192 + tid];
    int sl = (blockIdx.x & 7) << 7;
    atomicAdd(&sums[sl + tid], s);
    atomicAdd(&sums[sl + 64 + tid], q2);
  }
}

// ---------------- fast-path BN1+ReLU in place on bf16 y1, fin8 folded ----------------
__global__ __launch_bounds__(256) void hg_bnbf_k(unsigned short* __restrict__ y,
                                                 const float* __restrict__ sb,
                                                 const float* __restrict__ gm,
                                                 const float* __restrict__ bt) {
  __shared__ float sc[64], sh[64];
  int tid = threadIdx.x;
  if (tid < 64) {
    float s = 0.f, q2 = 0.f;
    for (int k = 0; k < 8; ++k) { s += sb[(k << 7) + tid]; q2 += sb[(k << 7) + 64 + tid]; }
    float invN = 1.f / 262144.f;
    float mean = s * invN;
    float var  = q2 * invN - mean * mean;
    float scl = gm[tid] * rsqrtf(var + 1e-3f);
    sc[tid] = scl; sh[tid] = bt[tid] - mean * scl;
  }
  __syncthreads();
  size_t i = ((size_t)blockIdx.x * 256 + tid) << 3;
  int c0 = (int)(i & 63);
  uint4 v = *(uint4*)(y + i);
  unsigned int u[4] = {v.x, v.y, v.z, v.w};
  for (int q = 0; q < 4; ++q) {
    int c = c0 + q * 2;
    float f0 = sc[c] * bf2f((unsigned short)(u[q] & 0xFFFFu)) + sh[c];
    float f1 = sc[c + 1] * bf2f((unsigned short)(u[q] >> 16)) + sh[c + 1];
    u[q] = pk2(f0 > 0.f ? f0 : 0.f, f1 > 0.f ? f1 : 0.f);
  }
  *(uint4*)(y + i) = make_uint4(u[0], u[1], u[2], u[3]);
}

// ---------------- fast-path BN2+ReLU on fp32 out, fin8 folded ----------------
__global__ __launch_bounds__(256) void hg_bnrf_k(float* __restrict__ y,
                                                 const float* __restrict__ sb,
                                                 const float* __restrict__ gm,
                                                 const float* __restrict__ bt) {
  __shared__ float sc[64], sh[64];
  int tid = threadIdx.x;
  if (tid < 64) {
    float s = 0.f, q2 = 0.f;
    for (int k = 0; k < 8; ++k) { s += sb[(k << 7) + tid]; q2 += sb[(k << 7) + 64 + tid]; }
    float invN = 1.f / 262144.f;
    float mean = s * invN;
    float var  = q2 * invN - mean * mean;
    float scl = gm[tid] * rsqrtf(var + 1e-3f);
    sc[tid] = scl; sh[tid] = bt[tid] - mean * scl;
  }
  __syncthreads();
  size_t i = (size_t)blockIdx.x * 256 + tid;  // float4 index
  int c4 = ((int)i & 15) << 2;
  float4 v = *(float4*)(y + i * 4);
  float f;
  f = sc[c4]     * v.x + sh[c4];     v.x = f > 0.f ? f : 0.f;
  f = sc[c4 + 1] * v.y + sh[c4 + 1]; v.y = f > 0.f ? f : 0.f;
  f = sc[c4 + 2] * v.z + sh[c4 + 2]; v.z = f > 0.f ? f : 0.f;
  f = sc[c4 + 3] * v.w + sh[c4 + 3]; v.w = f > 0.f ? f : 0.f;
  *(float4*)(y + i * 4) = v;
}

// ================= fallback path (unchanged, ws too small) =================
__global__ __launch_bounds__(256) void hg_wt_k(const float* __restrict__ w1,
                                               const float* __restrict__ w2,
                                               unsigned short* __restrict__ wt1,
                                               unsigned short* __restrict__ wt2) {
  __shared__ short T[64 * ASTR];
  int blk = blockIdx.x;
  int sel = blk >= 108;
  const float* w = sel ? w2 : w1;
  unsigned short* wt = sel ? wt2 : wt1;
  int bt = sel ? blk - 108 : blk;
  const float* src = w + (size_t)bt * 8192;
  int tid = threadIdx.x;
  int co = tid & 63;
  int c0 = tid >> 6;
  for (int i = 0; i < 32; ++i) {
    int ci = c0 + (i << 2);
    T[co * ASTR + ci] = (short)f2b(src[(size_t)ci * 64 + co]);
  }
  __syncthreads();
  unsigned short* dst = wt + (size_t)bt * 8192;
  for (int i = 0; i < 4; ++i) {
    int task = tid + (i << 8);
    int row = task >> 4, q = task & 15;
    *(uint4*)(dst + row * 128 + (q << 3)) = *(const uint4*)&T[row * ASTR + (q << 3)];
  }
}

__global__ __launch_bounds__(256) void hg_conv_o_k(
    const float* __restrict__ xf, const unsigned short* __restrict__ y1n,
    const float* __restrict__ skip, const float* __restrict__ wf,
    const unsigned short* __restrict__ wt, const float* __restrict__ bn,
    unsigned short* __restrict__ outb, float* __restrict__ outf,
    int mode, int has_wt) {
  __shared__ short Al[132 * ASTR];
  __shared__ short Wl[64 * WSTR];
  __shared__ float sbl[128];
  int tid = threadIdx.x;
  int xcd = blockIdx.x & 7, slot = blockIdx.x >> 3;
  int b = xcd & 3;
  int t = ((xcd >> 2) << 8) + slot;
  int m0 = (b << 16) + (t << 7);
  int od  = (t >> 5) & 15;
  int oh0 = (t << 1) & 63;
  int lane = tid & 63, quad = lane >> 4, l16 = lane & 15;
  int wm = (tid >> 6) << 5;

  if (mode == 1 && tid < 128) sbl[tid] = bn[tid];

  f32x4 acc[2][4];
  for (int i = 0; i < 2; ++i)
    for (int j = 0; j < 4; ++j) acc[i][j] = (f32x4){0.f, 0.f, 0.f, 0.f};

  const float* wbf = wf + (size_t)b * 27 * 8192;
  const unsigned short* wbt = wt + (size_t)b * 27 * 8192;

  for (int kd = 0; kd < 3; ++kd) {
    int ud = od + kd - 1;
    int dok = (ud >= 0 && ud < 16);
    for (int kh = 0; kh < 3; ++kh) {
      __syncthreads();
      for (int i = 0; i < 9; ++i) {
        int task = tid + (i << 8);
        if (task < 2112) {
          int chunk = task & 15;
          int pos = task >> 4;
          int g = (pos >= 66) ? 1 : 0;
          int uwi = pos - (g ? 66 : 0);
          int uh = oh0 + g + kh - 1;
          int uw = uwi - 1;
          uint4 val = make_uint4(0u, 0u, 0u, 0u);
          if (dok && (unsigned)uh < 64u && (unsigned)uw < 64u) {
            if (mode == 0) {
              size_t src = ((((size_t)(b * 8 + (ud >> 1))) * 32 + (uh >> 1)) * 32 +
                            (uw >> 1)) * 128 + (chunk << 3);
              float4 f0 = *(const float4*)(xf + src);
              float4 f1 = *(const float4*)(xf + src + 4);
              val.x = pk2(f0.x, f0.y); val.y = pk2(f0.z, f0.w);
              val.z = pk2(f1.x, f1.y); val.w = pk2(f1.z, f1.w);
            } else {
              size_t srow = (((size_t)(b * 16 + ud)) * 64 + uh) * 64 + uw;
              if (chunk < 8) {
                uint4 raw = *(const uint4*)(y1n + srow * 64 + (chunk << 3));
                unsigned int u[4] = {raw.x, raw.y, raw.z, raw.w};
                unsigned int o[4];
                int c0 = chunk << 3;
                for (int q = 0; q < 4; ++q) {
                  int c = c0 + q * 2;
                  float f0 = sbl[c] * bf2f((unsigned short)(u[q] & 0xFFFFu)) + sbl[64 + c];
                  float f1 = sbl[c + 1] * bf2f((unsigned short)(u[q] >> 16)) + sbl[64 + c + 1];
                  o[q] = pk2(f0 > 0.f ? f0 : 0.f, f1 > 0.f ? f1 : 0.f);
                }
                val = make_uint4(o[0], o[1], o[2], o[3]);
              } else {
                const float* sp = skip + srow * 64 + ((chunk - 8) << 3);
                float4 f0 = *(const float4*)(sp);
                float4 f1 = *(const float4*)(sp + 4);
                val.x = pk2(f0.x, f0.y); val.y = pk2(f0.z, f0.w);
                val.z = pk2(f1.x, f1.y); val.w = pk2(f1.z, f1.w);
              }
            }
          }
          *(uint4*)&Al[pos * ASTR + (chunk << 3)] = val;
        }
      }
      for (int kw = 0; kw < 3; ++kw) {
        if (kw) __syncthreads();
        int tap = (kd * 3 + kh) * 3 + kw;
        if (has_wt) {
          const unsigned short* wsrc = wbt + (size_t)tap * 8192;
          for (int i = 0; i < 4; ++i) {
            int task = tid + (i << 8);
            int co = task >> 4, q = task & 15;
            *(uint4*)&Wl[co * WSTR + (q << 3)] = *(const uint4*)(wsrc + co * 128 + (q << 3));
          }
        } else {
          const float* wp = wbf + (size_t)tap * 8192 + (tid & 63);
          int wco = tid & 63;
          int ci0 = (tid >> 6) << 5;
          for (int c = 0; c < 32; c += 2) {
            float f0 = wp[(size_t)(ci0 + c) * 64];
            float f1 = wp[(size_t)(ci0 + c + 1) * 64];
            *(unsigned int*)&Wl[wco * WSTR + ci0 + c] = pk2(f0, f1);
          }
        }
        __syncthreads();
        for (int k0 = 0; k0 < 128; k0 += 32) {
          int kk = k0 + (quad << 3);
          union { uint4 u; short8 s; } cv;
          short8 av[2];
          for (int mt = 0; mt < 2; ++mt) {
            int r = wm + (mt << 4) + l16;
            int g = r >> 6, ow = r & 63;
            cv.u = *(const uint4*)&Al[(g * 66 + ow + kw) * ASTR + kk];
            av[mt] = cv.s;
          }
          short8 bv[4];
          for (int nt = 0; nt < 4; ++nt) {
            int base = ((nt << 4) + l16) * WSTR + kk;
            uint2 lo = *(const uint2*)&Wl[base];
            uint2 hi = *(const uint2*)&Wl[base + 4];
            cv.u = make_uint4(lo.x, lo.y, hi.x, hi.y);
            bv[nt] = cv.s;
          }
          for (int mt = 0; mt < 2; ++mt)
            for (int nt = 0; nt < 4; ++nt)
              acc[mt][nt] = __builtin_amdgcn_mfma_f32_16x16x32_bf16(
                  av[mt], bv[nt], acc[mt][nt], 0, 0, 0);
        }
      }
    }
  }

  for (int mt = 0; mt < 2; ++mt) {
    int mbase = m0 + wm + (mt << 4) + (quad << 2);
    for (int nt = 0; nt < 4; ++nt) {
      int n = (nt << 4) + l16;
      for (int r = 0; r < 4; ++r) {
        float v = acc[mt][nt][r];
        size_t o = (size_t)(mbase + r) * 64 + n;
        if (mode == 0) outb[o] = f2b(v);
        else outf[o] = v;
      }
    }
  }
}

__global__ void hg_zero_k(float* __restrict__ p, int n) {
  for (int i = threadIdx.x; i < n; i += 256) p[i] = 0.f;
}

__global__ __launch_bounds__(256) void hg_stats_k(const unsigned short* __restrict__ yb,
                                                  const float* __restrict__ yf, int isf,
                                                  float* __restrict__ sums) {
  int t = threadIdx.x;
  int c = t & 63;
  int r0 = blockIdx.x * 4 + (t >> 6);
  float sum = 0.f, ss = 0.f;
  for (int r = r0; r < 262144; r += 4096) {
    size_t idx = (size_t)r * 64 + c;
    float v = isf ? yf[idx] : bf2f(yb[idx]);
    sum += v; ss += v * v;
  }
  atomicAdd(&sums[c], sum);
  atomicAdd(&sums[64 + c], ss);
}

__global__ void hg_fin_k(float* __restrict__ sb, const float* __restrict__ gm,
                         const float* __restrict__ bt) {
  int c = threadIdx.x;  // 64
  float invN = 1.f / 262144.f;
  float mean = sb[c] * invN;
  float var  = sb[64 + c] * invN - mean * mean;
  float sc = gm[c] * rsqrtf(var + 1e-3f);
  sb[c] = sc;
  sb[64 + c] = bt[c] - mean * sc;
}

__global__ __launch_bounds__(256) void hg_bnb_k(unsigned short* __restrict__ y,
                                                const float* __restrict__ sb) {
  size_t i = ((size_t)blockIdx.x * 256 + threadIdx.x) << 3;
  int c0 = (int)(i & 63);
  uint4 v = *(uint4*)(y + i);
  unsigned int u[4] = {v.x, v.y, v.z, v.w};
  for (int q = 0; q < 4; ++q) {
    int c = c0 + q * 2;
    float f0 = sb[c] * bf2f((unsigned short)(u[q] & 0xFFFFu)) + sb[64 + c];
    float f1 = sb[c + 1] * bf2f((unsigned short)(u[q] >> 16)) + sb[64 + c + 1];
    u[q] = pk2(f0 > 0.f ? f0 : 0.f, f1 > 0.f ? f1 : 0.f);
  }
  *(uint4*)(y + i) = make_uint4(u[0], u[1], u[2], u[3]);
}

__global__ __launch_bounds__(256) void hg_bnrelu_f_k(float* __restrict__ y,
                                                     const float* __restrict__ sb) {
  size_t i = (size_t)blockIdx.x * 256 + threadIdx.x;  // float4 index
  int c4 = ((int)i & 15) << 2;
  float4 v = *(float4*)(y + i * 4);
  float f;
  f = sb[c4]     * v.x + sb[64 + c4];     v.x = f > 0.f ? f : 0.f;
  f = sb[c4 + 1] * v.y + sb[64 + c4 + 1]; v.y = f > 0.f ? f : 0.f;
  f = sb[c4 + 2] * v.z + sb[64 + c4 + 2]; v.z = f > 0.f ? f : 0.f;
  f = sb[c4 + 3] * v.w + sb[64 + c4 + 3]; v.w = f > 0.f ? f : 0.f;
  *(float4*)(y + i * 4) = v;
}

extern "C" void kernel_launch(void* const* d_in, const int* in_sizes, int n_in,
                              void* d_out, int out_size, void* d_ws, size_t ws_size,
                              hipStream_t stream) {
  (void)out_size;
  int ix = 0, iw1 = 1, iw2 = 2, isk = 3, ig1 = 4, ib1 = 5, ig2 = 6, ib2 = 7;
  if (n_in >= 9 && in_sizes[0] == 4194304 && in_sizes[1] == 884736 &&
      in_sizes[3] == 16777216 && in_sizes[4] == 64) {
    // insertion order
  } else if (n_in >= 9 && in_sizes[0] == 64 && in_sizes[4] == 16777216 &&
             in_sizes[6] == 884736 && in_sizes[8] == 4194304) {
    ib1 = 0; ib2 = 1; ig1 = 2; ig2 = 3; isk = 4; iw1 = 6; iw2 = 7; ix = 8;
  } else {
    return;
  }
  if (ws_size < (32ull << 20) + 2048ull) return;

  const float* x    = (const float*)d_in[ix];
  const float* w1   = (const float*)d_in[iw1];
  const float* w2   = (const float*)d_in[iw2];
  const float* skip = (const float*)d_in[isk];
  const float* g1   = (const float*)d_in[ig1];
  const float* b1   = (const float*)d_in[ib1];
  const float* g2   = (const float*)d_in[ig2];
  const float* b2   = (const float*)d_in[ib2];
  float* out = (float*)d_out;

  // fast-path layout
  const size_t OFF_SUMS = 32ull << 20;            // 8 KiB: 2 layers x 8 slots x 128 f32
  const size_t OFF_ZB   = OFF_SUMS + 8192;        // zero16 region (256 B)
  const size_t OFF_WT2  = OFF_ZB + 256;           // wt2 transposed
  const size_t OFF_XB   = OFF_WT2 + 2ull * 1769472;
  const size_t OFF_SKB  = OFF_XB + 8388608;       // 4194304 bf16
  const size_t OFF_WC1  = OFF_SKB + 33554432;     // 16777216 bf16
  const size_t NEED     = OFF_WC1 + 4194304;      // ~79.4 MB

  unsigned short* y1 = (unsigned short*)d_ws;     // 32 MiB bf16

  if (ws_size >= NEED) {
    // -------- fast path: 5 dispatches --------
    float* sums  = (float*)((char*)d_ws + OFF_SUMS);
    float* sums1 = sums;                          // 8 slots x 128
    float* sums2 = sums + 1024;                   // 8 slots x 128
    unsigned short* zb  = (unsigned short*)((char*)d_ws + OFF_ZB);
    unsigned short* wt2 = (unsigned short*)((char*)d_ws + OFF_WT2);
    unsigned short* xb  = (unsigned short*)((char*)d_ws + OFF_XB);
    unsigned short* skb = (unsigned short*)((char*)d_ws + OFF_SKB);
    unsigned short* wc1 = (unsigned short*)((char*)d_ws + OFF_WC1);

    hg_prep_k<<<10605, 256, 0, stream>>>(x, skip, w1, w2, xb, skb, wt2, wc1, sums);
    hg_c1p_k<<<1024, 256, 0, stream>>>(xb, wc1, zb, y1, sums1);
    hg_bnbf_k<<<8192, 256, 0, stream>>>(y1, sums1, g1, b1);
    hg_convf_k<<<2048, 256, 0, stream>>>(y1, skb, wt2, zb, out, sums2);
    hg_bnrf_k<<<16384, 256, 0, stream>>>(out, sums2, g2, b2);
  } else {
    // -------- fallback: R9 path (original layout) --------
    float* sums  = (float*)((char*)d_ws + (32ull << 20));
    float* sums1 = sums;
    float* sums2 = sums + 128;
    unsigned short* wt1 = (unsigned short*)((char*)d_ws + (32ull << 20) + 2048ull);
    unsigned short* wt2 = wt1 + 884736ull;
    const size_t WS_NEED = (32ull << 20) + 2048ull + 2ull * 884736ull * 2ull;
    int has_wt = (ws_size >= WS_NEED) ? 1 : 0;

    hg_zero_k<<<1, 256, 0, stream>>>(sums, 512);
    if (has_wt) hg_wt_k<<<216, 256, 0, stream>>>(w1, w2, wt1, wt2);
    hg_conv_o_k<<<2048, 256, 0, stream>>>(x, y1, skip, w1, wt1, sums1, y1, out, 0, has_wt);
    hg_stats_k<<<1024, 256, 0, stream>>>(y1, out, 0, sums1);
    hg_fin_k<<<1, 64, 0, stream>>>(sums1, g1, b1);
    hg_conv_o_k<<<2048, 256, 0, stream>>>(x, y1, skip, w2, wt2, sums1, y1, out, 1, has_wt);
    hg_stats_k<<<1024, 256, 0, stream>>>(y1, out, 1, sums2);
    hg_fin_k<<<1, 64, 0, stream>>>(sums2, g2, b2);
    hg_bnrelu_f_k<<<16384, 256, 0, stream>>>(out, sums2);
  }
}

// Round 10
// 387.284 us; speedup vs baseline: 1.3544x; 1.0917x over previous
//
#include <hip/hip_runtime.h>

// HyperGANUpBlock (all fp32 I/O): x[4,8,32,32,128] -> up2 -> conv3^3(128->64, per-sample
// w1) -> BN(train,1e-3)+ReLU -> concat skip -> conv3^3(128->64, per-sample w2) -> BN+ReLU.
// R19: c1p B-read coalescing. wc1 stored FRAGMENT-MAJOR [mat][cq][co][8ci] (R16's wtg
// layout): each bv wave-read becomes 4x256B contiguous (was 16x64B scattered) -> fixes
// the suspected transaction/latency bound in c1p (est ~120-145us, hidden below convf's
// top-5 cutoff; MFMA floor is 14us). conv2 kept at R18 (32x32x16, ~149us, within ~25%
// of its LDS-pipe floor at 3 blk/CU). 5 dispatches, parity conv1, fused prep+fin8.
// ws(fast): y1 32Mi | sums 8Ki | zb 256B | wt2 1.7Mi | (spare) | xb | skb | wc1.

typedef __attribute__((ext_vector_type(8))) short short8;
typedef __attribute__((ext_vector_type(4))) float f32x4;
typedef __attribute__((ext_vector_type(16))) float f32x16;

__device__ __forceinline__ float bf2f(unsigned short u) {
  union { unsigned int i; float f; } v; v.i = ((unsigned int)u) << 16; return v.f;
}
__device__ __forceinline__ unsigned short f2b(float f) {
  union { float ff; unsigned int u; } v; v.ff = f;
  unsigned int x = v.u;
  return (unsigned short)((x + 0x7FFFu + ((x >> 16) & 1u)) >> 16);  // RNE
}
__device__ __forceinline__ unsigned int pk2(float a, float b) {
  return (unsigned int)f2b(a) | ((unsigned int)f2b(b) << 16);
}
__device__ __forceinline__ void gload16(const void* g, void* l) {
  __builtin_amdgcn_global_load_lds(
      (const __attribute__((address_space(1))) void*)g,
      (__attribute__((address_space(3))) void*)l, 16, 0, 0);
}

#define ASTR 136  // transpose-scratch row stride (shorts)
#define WSTR 132  // old-path W row stride (shorts)

// ---------------- fast-path prep mega-kernel ----------------
// blocks [0,8192): skip->skb | [8192,10240): x->xb | [10240,10348): w2->wt2 transpose
// [10348,10604): w1->wc1 parity-combine (FRAGMENT-MAJOR) | [10604]: zero sums+zb
__global__ __launch_bounds__(256) void hg_prep_k(
    const float* __restrict__ x, const float* __restrict__ skip,
    const float* __restrict__ w1, const float* __restrict__ w2,
    unsigned short* __restrict__ xb, unsigned short* __restrict__ skb,
    unsigned short* __restrict__ wt2, unsigned short* __restrict__ wc1,
    float* __restrict__ sums) {
  __shared__ short T[64 * ASTR];
  int blk = blockIdx.x;
  int tid = threadIdx.x;
  if (blk < 10240) {
    // fp32 -> bf16, 8 elem/thread
    const float* s; unsigned short* d; size_t i;
    if (blk < 8192) { s = skip; d = skb; i = ((size_t)blk * 256 + tid) << 3; }
    else            { s = x;    d = xb;  i = ((size_t)(blk - 8192) * 256 + tid) << 3; }
    float4 a = *(const float4*)(s + i);
    float4 c = *(const float4*)(s + i + 4);
    uint4 o;
    o.x = pk2(a.x, a.y); o.y = pk2(a.z, a.w);
    o.z = pk2(c.x, c.y); o.w = pk2(c.z, c.w);
    *(uint4*)(d + i) = o;
  } else if (blk < 10348) {
    // w2[bt,ci,co] -> wt2[bt,co,ci] bf16
    int bt = blk - 10240;
    const float* src = w2 + (size_t)bt * 8192;
    int co = tid & 63, c0 = tid >> 6;
    for (int i = 0; i < 32; ++i) {
      int ci = c0 + (i << 2);
      T[co * ASTR + ci] = (short)f2b(src[(size_t)ci * 64 + co]);
    }
    __syncthreads();
    unsigned short* dst = wt2 + (size_t)bt * 8192;
    for (int i = 0; i < 4; ++i) {
      int task = tid + (i << 8);
      int row = task >> 4, q = task & 15;
      *(uint4*)(dst + row * 128 + (q << 3)) = *(const uint4*)&T[row * ASTR + (q << 3)];
    }
  } else if (blk < 10604) {
    // parity-combined conv1 weights, FRAGMENT-MAJOR: wc1[m9][cq][co][8ci]
    // S(0,0)={0} S(0,1)={1,2} S(1,0)={0,1} S(1,1)={2}
    int m9 = blk - 10348;
    int b = m9 >> 6, m = m9 & 63;
    int dd = m >> 4, hh = (m >> 2) & 3, ww = m & 3;
    const int ks[4] = {0, 1, 0, 2}, kc[4] = {1, 2, 2, 1};
    int co = tid & 63, c0 = tid >> 6;
    const float* wb = w1 + (size_t)b * 27 * 8192;
    for (int i = 0; i < 32; ++i) {
      int ci = c0 + (i << 2);
      float s = 0.f;
      for (int a = 0; a < kc[dd]; ++a)
        for (int e = 0; e < kc[hh]; ++e)
          for (int c = 0; c < kc[ww]; ++c) {
            int tap = ((ks[dd] + a) * 3 + ks[hh] + e) * 3 + ks[ww] + c;
            s += wb[(size_t)tap * 8192 + (size_t)ci * 64 + co];
          }
      T[co * ASTR + ci] = (short)f2b(s);
    }
    __syncthreads();
    unsigned short* dst = wc1 + (size_t)m9 * 8192;
    for (int i = 0; i < 4; ++i) {
      int task = tid + (i << 8);
      int row = task >> 4, q = task & 15;   // row=co, q=cq
      *(uint4*)(dst + ((q << 6) + row) * 8) = *(const uint4*)&T[row * ASTR + (q << 3)];
    }
  } else {
    // zero sums (2048 f32) + zb (64 f32, contiguous after sums)
    for (int i = tid; i < 2112; i += 256) sums[i] = 0.f;
  }
}

// ---------------- conv1: parity decomposition over source x ----------------
__global__ __launch_bounds__(256, 3) void hg_c1p_k(
    const unsigned short* __restrict__ xb, const unsigned short* __restrict__ wc1,
    const unsigned short* __restrict__ zb, unsigned short* __restrict__ outb,
    float* __restrict__ sums) {
  __shared__ short Xl[2 * 100 * 128];   // 51200 B: 2 planes x 10x10 cells x 128ch
  int tid = threadIdx.x;
  int xcd = blockIdx.x & 7, slot = blockIdx.x >> 3;   // 1024 blocks
  int b = xcd & 3;
  int t = ((xcd >> 2) << 7) + slot;     // 0..255
  int od = t >> 4, hti = (t >> 2) & 3, wti = t & 3;
  int pd = od & 1, md = od >> 1;
  int lane = tid & 63, quad = lane >> 4, l16 = lane & 15;
  int wid = tid >> 6;
  int ph = wid >> 1, pw = wid & 1;

  for (int pl = 0; pl < 2; ++pl) {
    int sd = md + pd - 1 + pl;
    int dok = ((unsigned)sd < 8u);
    for (int i = 0; i < 7; ++i) {
      int task = tid + (i << 8);
      if (task < 1600) {                // 100 pos x 16 chunks
        int pos = task >> 4, pq = task & 15;
        int q = (pq & 8) | ((pq & 7) ^ (pos & 7));
        int sh = pos / 10, sw = pos - sh * 10;
        int h = (hti << 3) + sh - 1, w = (wti << 3) + sw - 1;
        const unsigned short* src = zb;
        if (dok && (unsigned)h < 32u && (unsigned)w < 32u)
          src = xb + ((((size_t)(b * 8 + sd)) * 32 + h) * 32 + w) * 128 + (q << 3);
        gload16(src, (char*)Xl + ((pl * 1600 + (i << 8) + (tid & 192)) << 4));
      }
    }
  }
  __syncthreads();                      // the ONLY staging barrier

  f32x4 acc[4][4];
#pragma unroll
  for (int i = 0; i < 4; ++i)
#pragma unroll
    for (int j = 0; j < 4; ++j) acc[i][j] = (f32x4){0.f, 0.f, 0.f, 0.f};

  const unsigned short* wcb = wc1 + ((size_t)b * 64 + (pd << 5) + (ph << 3) + (pw << 1)) * 8192;

  for (int td = 0; td < 2; ++td) {
    const char* Xp = (const char*)Xl + td * 25600;
    for (int th = 0; th < 2; ++th) {
      int hb = ph + th;
      for (int tw = 0; tw < 2; ++tw) {
        int wb2 = pw + tw;
        const unsigned short* wp = wcb + (size_t)((td << 4) + (th << 2) + tw) * 8192;
#pragma unroll
        for (int ksx = 0; ksx < 4; ++ksx) {
          int cq = (ksx << 2) + quad;
          short8 av[4], bv[4];
#pragma unroll
          for (int mt = 0; mt < 4; ++mt) {
            int pos = ((mt << 1) + (l16 >> 3) + hb) * 10 + (l16 & 7) + wb2;
            int pc = (cq & 8) | ((cq & 7) ^ (pos & 7));
            av[mt] = *(const short8*)(Xp + pos * 256 + (pc << 4));
          }
#pragma unroll
          for (int nt = 0; nt < 4; ++nt)
            bv[nt] = *(const short8*)(wp + (((cq << 6) + (nt << 4) + l16) << 3));
#pragma unroll
          for (int mt = 0; mt < 4; ++mt)
#pragma unroll
            for (int nt = 0; nt < 4; ++nt)
              acc[mt][nt] = __builtin_amdgcn_mfma_f32_16x16x32_bf16(
                  av[mt], bv[nt], acc[mt][nt], 0, 0, 0);
        }
      }
    }
  }

  __syncthreads();                      // Xl reads done -> stats scratch
  float* sbf = (float*)Xl;
  int rowb = (b * 16 + od) * 64;
#pragma unroll
  for (int nt = 0; nt < 4; ++nt) {
    int n = (nt << 4) + l16;
    float s = 0.f, q2 = 0.f;
#pragma unroll
    for (int mt = 0; mt < 4; ++mt) {
      int mh = (mt << 1) + (quad >> 1);
      int oh = (((hti << 3) + mh) << 1) + ph;
      size_t rb = (size_t)(rowb + oh) * 64;
#pragma unroll
      for (int r = 0; r < 4; ++r) {
        float v = acc[mt][nt][r];
        int ow = (((wti << 3) + ((quad & 1) << 2) + r) << 1) + pw;
        outb[(rb + ow) * 64 + n] = f2b(v);
        s += v; q2 += v * v;
      }
    }
    s += __shfl_xor(s, 16); s += __shfl_xor(s, 32);
    q2 += __shfl_xor(q2, 16); q2 += __shfl_xor(q2, 32);
    if (quad == 0) { sbf[wid * 128 + n] = s; sbf[wid * 128 + 64 + n] = q2; }
  }
  __syncthreads();
  if (tid < 64) {
    float s = sbf[tid] + sbf[128 + tid] + sbf[256 + tid] + sbf[384 + tid];
    float q2 = sbf[64 + tid] + sbf[192 + tid] + sbf[320 + tid] + sbf[448 + tid];
    int sl = (blockIdx.x & 7) << 7;
    atomicAdd(&sums[sl + tid], s);
    atomicAdd(&sums[sl + 64 + tid], q2);
  }
}

// ---------------- conv2: 32x32x16 MFMA, (row-half x k-half) waves ----------------
__global__ __launch_bounds__(256) void hg_convf_k(
    const unsigned short* __restrict__ y1n, const unsigned short* __restrict__ skb,
    const unsigned short* __restrict__ wt, const unsigned short* __restrict__ zb,
    float* __restrict__ outf, float* __restrict__ sums) {
  __shared__ short Al[132 * 128];  // 33792 B, unpadded, chunk-swizzled
  __shared__ short Wl[64 * 128];   // 16384 B, unpadded, chunk-swizzled
  int tid = threadIdx.x;
  int xcd = blockIdx.x & 7, slot = blockIdx.x >> 3;
  int b = xcd & 3;
  int t = ((xcd >> 2) << 8) + slot;       // 0..511 tile within sample
  int m0 = (b << 16) + (t << 7);
  int od  = (t >> 5) & 15;
  int oh0 = (t << 1) & 63;
  int lane = tid & 63, l32 = lane & 31, lh = lane >> 5;
  int wid = tid >> 6;
  int wh = wid & 1;                   // row half: rows wh*64 .. +63
  int ks = wid >> 1;                  // k half: chunks ks*8 .. +7

  f32x16 acc[2][2];
#pragma unroll
  for (int e = 0; e < 16; ++e) {
    acc[0][0][e] = 0.f; acc[0][1][e] = 0.f; acc[1][0][e] = 0.f; acc[1][1][e] = 0.f;
  }

  const unsigned short* wb = wt + (size_t)b * 27 * 8192;

  for (int kd = 0; kd < 3; ++kd) {
    int ud = od + kd - 1;
    int dok = ((unsigned)ud < 16u);
    for (int kh = 0; kh < 3; ++kh) {
      __syncthreads();  // prior MFMAs done before Al/Wl overwrite
      for (int i = 0; i < 9; ++i) {
        int task = tid + (i << 8);
        if (task < 2112) {
          int pos = task >> 4, pq = task & 15;
          int q = (pq & 8) | ((pq & 7) ^ (pos & 7));  // logical chunk (involution)
          int g = (pos >= 66) ? 1 : 0;
          int uw = pos - (g ? 66 : 0) - 1;
          int uh = oh0 + g + kh - 1;
          const unsigned short* src = zb;
          if (dok && (unsigned)uh < 64u && (unsigned)uw < 64u) {
            size_t srow = (((size_t)(b * 16 + ud)) * 64 + uh) * 64 + uw;
            src = (q < 8) ? (y1n + srow * 64 + (q << 3))
                          : (skb + srow * 64 + ((q - 8) << 3));
          }
          gload16(src, (char*)Al + (((i << 8) + (tid & 192)) << 4));
        }
      }
      for (int kw = 0; kw < 3; ++kw) {
        if (kw) __syncthreads();
        int tap = (kd * 3 + kh) * 3 + kw;
        const unsigned short* wsrc = wb + (size_t)tap * 8192;
        {
          int co0 = tid >> 4, pq = tid & 15;
          for (int i = 0; i < 4; ++i) {
            int co = co0 + (i << 4);
            int q = (pq & 8) | ((pq & 7) ^ (co & 7));
            gload16(wsrc + co * 128 + (q << 3),
                    (char*)Wl + (((i << 8) + (tid & 192)) << 4));
          }
        }
        __syncthreads();
        // 4 K=16 steps x (2 m x 2 n) 32-tiles
#pragma unroll
        for (int kt = 0; kt < 4; ++kt) {
          int ch = (ks << 3) + (kt << 1) + lh;   // logical chunk 0..15
          short8 av[2], bv[2];
#pragma unroll
          for (int mt = 0; mt < 2; ++mt) {
            int r = (wh << 6) + (mt << 5) + l32;
            int pos = (r >> 6) * 66 + (r & 63) + kw;
            int pc = (ch & 8) | ((ch & 7) ^ (pos & 7));
            av[mt] = *(const short8*)((const char*)Al + pos * 256 + (pc << 4));
          }
#pragma unroll
          for (int nt = 0; nt < 2; ++nt) {
            int co = (nt << 5) + l32;
            int pc = (ch & 8) | ((ch & 7) ^ (co & 7));
            bv[nt] = *(const short8*)((const char*)Wl + co * 256 + (pc << 4));
          }
#pragma unroll
          for (int mt = 0; mt < 2; ++mt)
#pragma unroll
            for (int nt = 0; nt < 2; ++nt)
              acc[mt][nt] = __builtin_amdgcn_mfma_f32_32x32x16_bf16(
                  av[mt], bv[nt], acc[mt][nt], 0, 0, 0);
        }
      }
    }
  }

  // ---- k-half combine: ks=1 dump to Al (16 pieces x 128 slots x 16B, conflict-free) ----
  __syncthreads();                      // all MFMAs / Al reads done
  if (ks == 1) {
    char* base = (char*)Al + (((wh << 6) + lane) << 4);
#pragma unroll
    for (int mt = 0; mt < 2; ++mt)
#pragma unroll
      for (int nt = 0; nt < 2; ++nt)
#pragma unroll
        for (int r4 = 0; r4 < 4; ++r4) {
          f32x4 v = {acc[mt][nt][(r4 << 2)], acc[mt][nt][(r4 << 2) + 1],
                     acc[mt][nt][(r4 << 2) + 2], acc[mt][nt][(r4 << 2) + 3]};
          *(f32x4*)(base + ((((mt << 1) + nt) << 2) + r4) * 2048) = v;
        }
  }
  __syncthreads();
  float* sbf = (float*)Wl;              // stats scratch (disjoint from Al)
  if (ks == 0) {
    const char* base = (const char*)Al + (((wh << 6) + lane) << 4);
#pragma unroll
    for (int mt = 0; mt < 2; ++mt)
#pragma unroll
      for (int nt = 0; nt < 2; ++nt)
#pragma unroll
        for (int r4 = 0; r4 < 4; ++r4) {
          f32x4 v = *(const f32x4*)(base + ((((mt << 1) + nt) << 2) + r4) * 2048);
#pragma unroll
          for (int j = 0; j < 4; ++j) acc[mt][nt][(r4 << 2) + j] += v[j];
        }
    // write + stats. C/D: col = lane&31, row = (reg&3) + 8*(reg>>2) + 4*lh
#pragma unroll
    for (int nt = 0; nt < 2; ++nt) {
      int n = (nt << 5) + l32;
      float s = 0.f, q2 = 0.f;
#pragma unroll
      for (int mt = 0; mt < 2; ++mt) {
        int rbase = m0 + (wh << 6) + (mt << 5) + (lh << 2);
#pragma unroll
        for (int r = 0; r < 16; ++r) {
          float v = acc[mt][nt][r];
          int row = rbase + (r & 3) + ((r >> 2) << 3);
          outf[(size_t)row * 64 + n] = v;
          s += v; q2 += v * v;
        }
      }
      s += __shfl_xor(s, 32);
      q2 += __shfl_xor(q2, 32);
      if (lh == 0) { sbf[(wh << 7) + n] = s; sbf[(wh << 7) + 64 + n] = q2; }
    }
  }
  __syncthreads();
  if (tid < 64) {
    float s = sbf[tid] + sbf[128 + tid];
    float q2 = sbf[64 + tid] + sbf[192 + tid];
    int sl = (blockIdx.x & 7) << 7;
    atomicAdd(&sums[sl + tid], s);
    atomicAdd(&sums[sl + 64 + tid], q2);
  }
}

// ---------------- fast-path BN1+ReLU in place on bf16 y1, fin8 folded ----------------
__global__ __launch_bounds__(256) void hg_bnbf_k(unsigned short* __restrict__ y,
                                                 const float* __restrict__ sb,
                                                 const float* __restrict__ gm,
                                                 const float* __restrict__ bt) {
  __shared__ float sc[64], sh[64];
  int tid = threadIdx.x;
  if (tid < 64) {
    float s = 0.f, q2 = 0.f;
    for (int k = 0; k < 8; ++k) { s += sb[(k << 7) + tid]; q2 += sb[(k << 7) + 64 + tid]; }
    float invN = 1.f / 262144.f;
    float mean = s * invN;
    float var  = q2 * invN - mean * mean;
    float scl = gm[tid] * rsqrtf(var + 1e-3f);
    sc[tid] = scl; sh[tid] = bt[tid] - mean * scl;
  }
  __syncthreads();
  size_t i = ((size_t)blockIdx.x * 256 + tid) << 3;
  int c0 = (int)(i & 63);
  uint4 v = *(uint4*)(y + i);
  unsigned int u[4] = {v.x, v.y, v.z, v.w};
  for (int q = 0; q < 4; ++q) {
    int c = c0 + q * 2;
    float f0 = sc[c] * bf2f((unsigned short)(u[q] & 0xFFFFu)) + sh[c];
    float f1 = sc[c + 1] * bf2f((unsigned short)(u[q] >> 16)) + sh[c + 1];
    u[q] = pk2(f0 > 0.f ? f0 : 0.f, f1 > 0.f ? f1 : 0.f);
  }
  *(uint4*)(y + i) = make_uint4(u[0], u[1], u[2], u[3]);
}

// ---------------- fast-path BN2+ReLU on fp32 out, fin8 folded ----------------
__global__ __launch_bounds__(256) void hg_bnrf_k(float* __restrict__ y,
                                                 const float* __restrict__ sb,
                                                 const float* __restrict__ gm,
                                                 const float* __restrict__ bt) {
  __shared__ float sc[64], sh[64];
  int tid = threadIdx.x;
  if (tid < 64) {
    float s = 0.f, q2 = 0.f;
    for (int k = 0; k < 8; ++k) { s += sb[(k << 7) + tid]; q2 += sb[(k << 7) + 64 + tid]; }
    float invN = 1.f / 262144.f;
    float mean = s * invN;
    float var  = q2 * invN - mean * mean;
    float scl = gm[tid] * rsqrtf(var + 1e-3f);
    sc[tid] = scl; sh[tid] = bt[tid] - mean * scl;
  }
  __syncthreads();
  size_t i = (size_t)blockIdx.x * 256 + tid;  // float4 index
  int c4 = ((int)i & 15) << 2;
  float4 v = *(float4*)(y + i * 4);
  float f;
  f = sc[c4]     * v.x + sh[c4];     v.x = f > 0.f ? f : 0.f;
  f = sc[c4 + 1] * v.y + sh[c4 + 1]; v.y = f > 0.f ? f : 0.f;
  f = sc[c4 + 2] * v.z + sh[c4 + 2]; v.z = f > 0.f ? f : 0.f;
  f = sc[c4 + 3] * v.w + sh[c4 + 3]; v.w = f > 0.f ? f : 0.f;
  *(float4*)(y + i * 4) = v;
}

// ================= fallback path (unchanged, ws too small) =================
__global__ __launch_bounds__(256) void hg_wt_k(const float* __restrict__ w1,
                                               const float* __restrict__ w2,
                                               unsigned short* __restrict__ wt1,
                                               unsigned short* __restrict__ wt2) {
  __shared__ short T[64 * ASTR];
  int blk = blockIdx.x;
  int sel = blk >= 108;
  const float* w = sel ? w2 : w1;
  unsigned short* wt = sel ? wt2 : wt1;
  int bt = sel ? blk - 108 : blk;
  const float* src = w + (size_t)bt * 8192;
  int tid = threadIdx.x;
  int co = tid & 63;
  int c0 = tid >> 6;
  for (int i = 0; i < 32; ++i) {
    int ci = c0 + (i << 2);
    T[co * ASTR + ci] = (short)f2b(src[(size_t)ci * 64 + co]);
  }
  __syncthreads();
  unsigned short* dst = wt + (size_t)bt * 8192;
  for (int i = 0; i < 4; ++i) {
    int task = tid + (i << 8);
    int row = task >> 4, q = task & 15;
    *(uint4*)(dst + row * 128 + (q << 3)) = *(const uint4*)&T[row * ASTR + (q << 3)];
  }
}

__global__ __launch_bounds__(256) void hg_conv_o_k(
    const float* __restrict__ xf, const unsigned short* __restrict__ y1n,
    const float* __restrict__ skip, const float* __restrict__ wf,
    const unsigned short* __restrict__ wt, const float* __restrict__ bn,
    unsigned short* __restrict__ outb, float* __restrict__ outf,
    int mode, int has_wt) {
  __shared__ short Al[132 * ASTR];
  __shared__ short Wl[64 * WSTR];
  __shared__ float sbl[128];
  int tid = threadIdx.x;
  int xcd = blockIdx.x & 7, slot = blockIdx.x >> 3;
  int b = xcd & 3;
  int t = ((xcd >> 2) << 8) + slot;
  int m0 = (b << 16) + (t << 7);
  int od  = (t >> 5) & 15;
  int oh0 = (t << 1) & 63;
  int lane = tid & 63, quad = lane >> 4, l16 = lane & 15;
  int wm = (tid >> 6) << 5;

  if (mode == 1 && tid < 128) sbl[tid] = bn[tid];

  f32x4 acc[2][4];
  for (int i = 0; i < 2; ++i)
    for (int j = 0; j < 4; ++j) acc[i][j] = (f32x4){0.f, 0.f, 0.f, 0.f};

  const float* wbf = wf + (size_t)b * 27 * 8192;
  const unsigned short* wbt = wt + (size_t)b * 27 * 8192;

  for (int kd = 0; kd < 3; ++kd) {
    int ud = od + kd - 1;
    int dok = (ud >= 0 && ud < 16);
    for (int kh = 0; kh < 3; ++kh) {
      __syncthreads();
      for (int i = 0; i < 9; ++i) {
        int task = tid + (i << 8);
        if (task < 2112) {
          int chunk = task & 15;
          int pos = task >> 4;
          int g = (pos >= 66) ? 1 : 0;
          int uwi = pos - (g ? 66 : 0);
          int uh = oh0 + g + kh - 1;
          int uw = uwi - 1;
          uint4 val = make_uint4(0u, 0u, 0u, 0u);
          if (dok && (unsigned)uh < 64u && (unsigned)uw < 64u) {
            if (mode == 0) {
              size_t src = ((((size_t)(b * 8 + (ud >> 1))) * 32 + (uh >> 1)) * 32 +
                            (uw >> 1)) * 128 + (chunk << 3);
              float4 f0 = *(const float4*)(xf + src);
              float4 f1 = *(const float4*)(xf + src + 4);
              val.x = pk2(f0.x, f0.y); val.y = pk2(f0.z, f0.w);
              val.z = pk2(f1.x, f1.y); val.w = pk2(f1.z, f1.w);
            } else {
              size_t srow = (((size_t)(b * 16 + ud)) * 64 + uh) * 64 + uw;
              if (chunk < 8) {
                uint4 raw = *(const uint4*)(y1n + srow * 64 + (chunk << 3));
                unsigned int u[4] = {raw.x, raw.y, raw.z, raw.w};
                unsigned int o[4];
                int c0 = chunk << 3;
                for (int q = 0; q < 4; ++q) {
                  int c = c0 + q * 2;
                  float f0 = sbl[c] * bf2f((unsigned short)(u[q] & 0xFFFFu)) + sbl[64 + c];
                  float f1 = sbl[c + 1] * bf2f((unsigned short)(u[q] >> 16)) + sbl[64 + c + 1];
                  o[q] = pk2(f0 > 0.f ? f0 : 0.f, f1 > 0.f ? f1 : 0.f);
                }
                val = make_uint4(o[0], o[1], o[2], o[3]);
              } else {
                const float* sp = skip + srow * 64 + ((chunk - 8) << 3);
                float4 f0 = *(const float4*)(sp);
                float4 f1 = *(const float4*)(sp + 4);
                val.x = pk2(f0.x, f0.y); val.y = pk2(f0.z, f0.w);
                val.z = pk2(f1.x, f1.y); val.w = pk2(f1.z, f1.w);
              }
            }
          }
          *(uint4*)&Al[pos * ASTR + (chunk << 3)] = val;
        }
      }
      for (int kw = 0; kw < 3; ++kw) {
        if (kw) __syncthreads();
        int tap = (kd * 3 + kh) * 3 + kw;
        if (has_wt) {
          const unsigned short* wsrc = wbt + (size_t)tap * 8192;
          for (int i = 0; i < 4; ++i) {
            int task = tid + (i << 8);
            int co = task >> 4, q = task & 15;
            *(uint4*)&Wl[co * WSTR + (q << 3)] = *(const uint4*)(wsrc + co * 128 + (q << 3));
          }
        } else {
          const float* wp = wbf + (size_t)tap * 8192 + (tid & 63);
          int wco = tid & 63;
          int ci0 = (tid >> 6) << 5;
          for (int c = 0; c < 32; c += 2) {
            float f0 = wp[(size_t)(ci0 + c) * 64];
            float f1 = wp[(size_t)(ci0 + c + 1) * 64];
            *(unsigned int*)&Wl[wco * WSTR + ci0 + c] = pk2(f0, f1);
          }
        }
        __syncthreads();
        for (int k0 = 0; k0 < 128; k0 += 32) {
          int kk = k0 + (quad << 3);
          union { uint4 u; short8 s; } cv;
          short8 av[2];
          for (int mt = 0; mt < 2; ++mt) {
            int r = wm + (mt << 4) + l16;
            int g = r >> 6, ow = r & 63;
            cv.u = *(const uint4*)&Al[(g * 66 + ow + kw) * ASTR + kk];
            av[mt] = cv.s;
          }
          short8 bv[4];
          for (int nt = 0; nt < 4; ++nt) {
            int base = ((nt << 4) + l16) * WSTR + kk;
            uint2 lo = *(const uint2*)&Wl[base];
            uint2 hi = *(const uint2*)&Wl[base + 4];
            cv.u = make_uint4(lo.x, lo.y, hi.x, hi.y);
            bv[nt] = cv.s;
          }
          for (int mt = 0; mt < 2; ++mt)
            for (int nt = 0; nt < 4; ++nt)
              acc[mt][nt] = __builtin_amdgcn_mfma_f32_16x16x32_bf16(
                  av[mt], bv[nt], acc[mt][nt], 0, 0, 0);
        }
      }
    }
  }

  for (int mt = 0; mt < 2; ++mt) {
    int mbase = m0 + wm + (mt << 4) + (quad << 2);
    for (int nt = 0; nt < 4; ++nt) {
      int n = (nt << 4) + l16;
      for (int r = 0; r < 4; ++r) {
        float v = acc[mt][nt][r];
        size_t o = (size_t)(mbase + r) * 64 + n;
        if (mode == 0) outb[o] = f2b(v);
        else outf[o] = v;
      }
    }
  }
}

__global__ void hg_zero_k(float* __restrict__ p, int n) {
  for (int i = threadIdx.x; i < n; i += 256) p[i] = 0.f;
}

__global__ __launch_bounds__(256) void hg_stats_k(const unsigned short* __restrict__ yb,
                                                  const float* __restrict__ yf, int isf,
                                                  float* __restrict__ sums) {
  int t = threadIdx.x;
  int c = t & 63;
  int r0 = blockIdx.x * 4 + (t >> 6);
  float sum = 0.f, ss = 0.f;
  for (int r = r0; r < 262144; r += 4096) {
    size_t idx = (size_t)r * 64 + c;
    float v = isf ? yf[idx] : bf2f(yb[idx]);
    sum += v; ss += v * v;
  }
  atomicAdd(&sums[c], sum);
  atomicAdd(&sums[64 + c], ss);
}

__global__ void hg_fin_k(float* __restrict__ sb, const float* __restrict__ gm,
                         const float* __restrict__ bt) {
  int c = threadIdx.x;  // 64
  float invN = 1.f / 262144.f;
  float mean = sb[c] * invN;
  float var  = sb[64 + c] * invN - mean * mean;
  float sc = gm[c] * rsqrtf(var + 1e-3f);
  sb[c] = sc;
  sb[64 + c] = bt[c] - mean * sc;
}

__global__ __launch_bounds__(256) void hg_bnb_k(unsigned short* __restrict__ y,
                                                const float* __restrict__ sb) {
  size_t i = ((size_t)blockIdx.x * 256 + threadIdx.x) << 3;
  int c0 = (int)(i & 63);
  uint4 v = *(uint4*)(y + i);
  unsigned int u[4] = {v.x, v.y, v.z, v.w};
  for (int q = 0; q < 4; ++q) {
    int c = c0 + q * 2;
    float f0 = sb[c] * bf2f((unsigned short)(u[q] & 0xFFFFu)) + sb[64 + c];
    float f1 = sb[c + 1] * bf2f((unsigned short)(u[q] >> 16)) + sb[64 + c + 1];
    u[q] = pk2(f0 > 0.f ? f0 : 0.f, f1 > 0.f ? f1 : 0.f);
  }
  *(uint4*)(y + i) = make_uint4(u[0], u[1], u[2], u[3]);
}

__global__ __launch_bounds__(256) void hg_bnrelu_f_k(float* __restrict__ y,
                                                     const float* __restrict__ sb) {
  size_t i = (size_t)blockIdx.x * 256 + threadIdx.x;  // float4 index
  int c4 = ((int)i & 15) << 2;
  float4 v = *(float4*)(y + i * 4);
  float f;
  f = sb[c4]     * v.x + sb[64 + c4];     v.x = f > 0.f ? f : 0.f;
  f = sb[c4 + 1] * v.y + sb[64 + c4 + 1]; v.y = f > 0.f ? f : 0.f;
  f = sb[c4 + 2] * v.z + sb[64 + c4 + 2]; v.z = f > 0.f ? f : 0.f;
  f = sb[c4 + 3] * v.w + sb[64 + c4 + 3]; v.w = f > 0.f ? f : 0.f;
  *(float4*)(y + i * 4) = v;
}

extern "C" void kernel_launch(void* const* d_in, const int* in_sizes, int n_in,
                              void* d_out, int out_size, void* d_ws, size_t ws_size,
                              hipStream_t stream) {
  (void)out_size;
  int ix = 0, iw1 = 1, iw2 = 2, isk = 3, ig1 = 4, ib1 = 5, ig2 = 6, ib2 = 7;
  if (n_in >= 9 && in_sizes[0] == 4194304 && in_sizes[1] == 884736 &&
      in_sizes[3] == 16777216 && in_sizes[4] == 64) {
    // insertion order
  } else if (n_in >= 9 && in_sizes[0] == 64 && in_sizes[4] == 16777216 &&
             in_sizes[6] == 884736 && in_sizes[8] == 4194304) {
    ib1 = 0; ib2 = 1; ig1 = 2; ig2 = 3; isk = 4; iw1 = 6; iw2 = 7; ix = 8;
  } else {
    return;
  }
  if (ws_size < (32ull << 20) + 2048ull) return;

  const float* x    = (const float*)d_in[ix];
  const float* w1   = (const float*)d_in[iw1];
  const float* w2   = (const float*)d_in[iw2];
  const float* skip = (const float*)d_in[isk];
  const float* g1   = (const float*)d_in[ig1];
  const float* b1   = (const float*)d_in[ib1];
  const float* g2   = (const float*)d_in[ig2];
  const float* b2   = (const float*)d_in[ib2];
  float* out = (float*)d_out;

  // fast-path layout
  const size_t OFF_SUMS = 32ull << 20;            // 8 KiB: 2 layers x 8 slots x 128 f32
  const size_t OFF_ZB   = OFF_SUMS + 8192;        // zero16 region (256 B)
  const size_t OFF_WT2  = OFF_ZB + 256;           // wt2 transposed
  const size_t OFF_XB   = OFF_WT2 + 2ull * 1769472;
  const size_t OFF_SKB  = OFF_XB + 8388608;       // 4194304 bf16
  const size_t OFF_WC1  = OFF_SKB + 33554432;     // 16777216 bf16
  const size_t NEED     = OFF_WC1 + 4194304;      // ~79.4 MB

  unsigned short* y1 = (unsigned short*)d_ws;     // 32 MiB bf16

  if (ws_size >= NEED) {
    // -------- fast path: 5 dispatches --------
    float* sums  = (float*)((char*)d_ws + OFF_SUMS);
    float* sums1 = sums;                          // 8 slots x 128
    float* sums2 = sums + 1024;                   // 8 slots x 128
    unsigned short* zb  = (unsigned short*)((char*)d_ws + OFF_ZB);
    unsigned short* wt2 = (unsigned short*)((char*)d_ws + OFF_WT2);
    unsigned short* xb  = (unsigned short*)((char*)d_ws + OFF_XB);
    unsigned short* skb = (unsigned short*)((char*)d_ws + OFF_SKB);
    unsigned short* wc1 = (unsigned short*)((char*)d_ws + OFF_WC1);

    hg_prep_k<<<10605, 256, 0, stream>>>(x, skip, w1, w2, xb, skb, wt2, wc1, sums);
    hg_c1p_k<<<1024, 256, 0, stream>>>(xb, wc1, zb, y1, sums1);
    hg_bnbf_k<<<8192, 256, 0, stream>>>(y1, sums1, g1, b1);
    hg_convf_k<<<2048, 256, 0, stream>>>(y1, skb, wt2, zb, out, sums2);
    hg_bnrf_k<<<16384, 256, 0, stream>>>(out, sums2, g2, b2);
  } else {
    // -------- fallback: R9 path (original layout) --------
    float* sums  = (float*)((char*)d_ws + (32ull << 20));
    float* sums1 = sums;
    float* sums2 = sums + 128;
    unsigned short* wt1 = (unsigned short*)((char*)d_ws + (32ull << 20) + 2048ull);
    unsigned short* wt2 = wt1 + 884736ull;
    const size_t WS_NEED = (32ull << 20) + 2048ull + 2ull * 884736ull * 2ull;
    int has_wt = (ws_size >= WS_NEED) ? 1 : 0;

    hg_zero_k<<<1, 256, 0, stream>>>(sums, 512);
    if (has_wt) hg_wt_k<<<216, 256, 0, stream>>>(w1, w2, wt1, wt2);
    hg_conv_o_k<<<2048, 256, 0, stream>>>(x, y1, skip, w1, wt1, sums1, y1, out, 0, has_wt);
    hg_stats_k<<<1024, 256, 0, stream>>>(y1, out, 0, sums1);
    hg_fin_k<<<1, 64, 0, stream>>>(sums1, g1, b1);
    hg_conv_o_k<<<2048, 256, 0, stream>>>(x, y1, skip, w2, wt2, sums1, y1, out, 1, has_wt);
    hg_stats_k<<<1024, 256, 0, stream>>>(y1, out, 1, sums2);
    hg_fin_k<<<1, 64, 0, stream>>>(sums2, g2, b2);
    hg_bnrelu_f_k<<<16384, 256, 0, stream>>>(out, sums2);
  }
}

// Round 11
// 386.426 us; speedup vs baseline: 1.3574x; 1.0022x over previous
//
#include <hip/hip_runtime.h>

// HyperGANUpBlock (all fp32 I/O): x[4,8,32,32,128] -> up2 -> conv3^3(128->64, per-sample
// w1) -> BN(train,1e-3)+ReLU -> concat skip -> conv3^3(128->64, per-sample w2) -> BN+ReLU.
// R20: prep coalescing + c1p setprio.
//  - prep wt2/wc1 sections: w reads made LINEAR (idx=tid+i*256 -> ci=idx>>6,co=idx&63,
//    coalesced) with LDS transpose; was stride-256B scalar (64B transaction per 4B used,
//    ~450MB transaction traffic in wc1 section).
//  - c1p: s_setprio(1) around MFMA cluster (T5; independent-block regime like attn m191).
//  - conv2 = R18 32x32x16 kernel (147us, near LDS-pipe floor at 3 blk/CU). 5 dispatches.
// ws(fast): y1 32Mi | sums 8Ki | zb 256B | wt2 1.7Mi | (spare) | xb | skb | wc1(frag-major).

typedef __attribute__((ext_vector_type(8))) short short8;
typedef __attribute__((ext_vector_type(4))) float f32x4;
typedef __attribute__((ext_vector_type(16))) float f32x16;

__device__ __forceinline__ float bf2f(unsigned short u) {
  union { unsigned int i; float f; } v; v.i = ((unsigned int)u) << 16; return v.f;
}
__device__ __forceinline__ unsigned short f2b(float f) {
  union { float ff; unsigned int u; } v; v.ff = f;
  unsigned int x = v.u;
  return (unsigned short)((x + 0x7FFFu + ((x >> 16) & 1u)) >> 16);  // RNE
}
__device__ __forceinline__ unsigned int pk2(float a, float b) {
  return (unsigned int)f2b(a) | ((unsigned int)f2b(b) << 16);
}
__device__ __forceinline__ void gload16(const void* g, void* l) {
  __builtin_amdgcn_global_load_lds(
      (const __attribute__((address_space(1))) void*)g,
      (__attribute__((address_space(3))) void*)l, 16, 0, 0);
}

#define ASTR 136  // transpose-scratch row stride (shorts)
#define WSTR 132  // old-path W row stride (shorts)

// ---------------- fast-path prep mega-kernel ----------------
// blocks [0,8192): skip->skb | [8192,10240): x->xb | [10240,10348): w2->wt2 transpose
// [10348,10604): w1->wc1 parity-combine (FRAGMENT-MAJOR) | [10604]: zero sums+zb
__global__ __launch_bounds__(256) void hg_prep_k(
    const float* __restrict__ x, const float* __restrict__ skip,
    const float* __restrict__ w1, const float* __restrict__ w2,
    unsigned short* __restrict__ xb, unsigned short* __restrict__ skb,
    unsigned short* __restrict__ wt2, unsigned short* __restrict__ wc1,
    float* __restrict__ sums) {
  __shared__ short T[64 * ASTR];
  int blk = blockIdx.x;
  int tid = threadIdx.x;
  if (blk < 10240) {
    // fp32 -> bf16, 8 elem/thread
    const float* s; unsigned short* d; size_t i;
    if (blk < 8192) { s = skip; d = skb; i = ((size_t)blk * 256 + tid) << 3; }
    else            { s = x;    d = xb;  i = ((size_t)(blk - 8192) * 256 + tid) << 3; }
    float4 a = *(const float4*)(s + i);
    float4 c = *(const float4*)(s + i + 4);
    uint4 o;
    o.x = pk2(a.x, a.y); o.y = pk2(a.z, a.w);
    o.z = pk2(c.x, c.y); o.w = pk2(c.z, c.w);
    *(uint4*)(d + i) = o;
  } else if (blk < 10348) {
    // w2[bt,ci,co] -> wt2[bt,co,ci] bf16 ; COALESCED linear read + LDS transpose
    int bt = blk - 10240;
    const float* src = w2 + (size_t)bt * 8192;
    for (int i = 0; i < 32; ++i) {
      int idx = tid + (i << 8);          // 0..8191 linear = ci*64+co
      int ci = idx >> 6, co = idx & 63;
      T[co * ASTR + ci] = (short)f2b(src[idx]);
    }
    __syncthreads();
    unsigned short* dst = wt2 + (size_t)bt * 8192;
    for (int i = 0; i < 4; ++i) {
      int task = tid + (i << 8);
      int row = task >> 4, q = task & 15;
      *(uint4*)(dst + row * 128 + (q << 3)) = *(const uint4*)&T[row * ASTR + (q << 3)];
    }
  } else if (blk < 10604) {
    // parity-combined conv1 weights, FRAGMENT-MAJOR: wc1[m9][cq][co][8ci]
    // S(0,0)={0} S(0,1)={1,2} S(1,0)={0,1} S(1,1)={2} ; COALESCED linear reads
    int m9 = blk - 10348;
    int b = m9 >> 6, m = m9 & 63;
    int dd = m >> 4, hh = (m >> 2) & 3, ww = m & 3;
    const int ks[4] = {0, 1, 0, 2}, kc[4] = {1, 2, 2, 1};
    const float* wb = w1 + (size_t)b * 27 * 8192;
    for (int i = 0; i < 32; ++i) {
      int idx = tid + (i << 8);          // linear = ci*64+co
      int ci = idx >> 6, co = idx & 63;
      float s = 0.f;
      for (int a = 0; a < kc[dd]; ++a)
        for (int e = 0; e < kc[hh]; ++e)
          for (int c = 0; c < kc[ww]; ++c) {
            int tap = ((ks[dd] + a) * 3 + ks[hh] + e) * 3 + ks[ww] + c;
            s += wb[(size_t)tap * 8192 + idx];
          }
      T[co * ASTR + ci] = (short)f2b(s);
    }
    __syncthreads();
    unsigned short* dst = wc1 + (size_t)m9 * 8192;
    for (int i = 0; i < 4; ++i) {
      int task = tid + (i << 8);
      int row = task >> 4, q = task & 15;   // row=co, q=cq
      *(uint4*)(dst + ((q << 6) + row) * 8) = *(const uint4*)&T[row * ASTR + (q << 3)];
    }
  } else {
    // zero sums (2048 f32) + zb (64 f32, contiguous after sums)
    for (int i = tid; i < 2112; i += 256) sums[i] = 0.f;
  }
}

// ---------------- conv1: parity decomposition over source x ----------------
__global__ __launch_bounds__(256, 3) void hg_c1p_k(
    const unsigned short* __restrict__ xb, const unsigned short* __restrict__ wc1,
    const unsigned short* __restrict__ zb, unsigned short* __restrict__ outb,
    float* __restrict__ sums) {
  __shared__ short Xl[2 * 100 * 128];   // 51200 B: 2 planes x 10x10 cells x 128ch
  int tid = threadIdx.x;
  int xcd = blockIdx.x & 7, slot = blockIdx.x >> 3;   // 1024 blocks
  int b = xcd & 3;
  int t = ((xcd >> 2) << 7) + slot;     // 0..255
  int od = t >> 4, hti = (t >> 2) & 3, wti = t & 3;
  int pd = od & 1, md = od >> 1;
  int lane = tid & 63, quad = lane >> 4, l16 = lane & 15;
  int wid = tid >> 6;
  int ph = wid >> 1, pw = wid & 1;

  for (int pl = 0; pl < 2; ++pl) {
    int sd = md + pd - 1 + pl;
    int dok = ((unsigned)sd < 8u);
    for (int i = 0; i < 7; ++i) {
      int task = tid + (i << 8);
      if (task < 1600) {                // 100 pos x 16 chunks
        int pos = task >> 4, pq = task & 15;
        int q = (pq & 8) | ((pq & 7) ^ (pos & 7));
        int sh = pos / 10, sw = pos - sh * 10;
        int h = (hti << 3) + sh - 1, w = (wti << 3) + sw - 1;
        const unsigned short* src = zb;
        if (dok && (unsigned)h < 32u && (unsigned)w < 32u)
          src = xb + ((((size_t)(b * 8 + sd)) * 32 + h) * 32 + w) * 128 + (q << 3);
        gload16(src, (char*)Xl + ((pl * 1600 + (i << 8) + (tid & 192)) << 4));
      }
    }
  }
  __syncthreads();                      // the ONLY staging barrier

  f32x4 acc[4][4];
#pragma unroll
  for (int i = 0; i < 4; ++i)
#pragma unroll
    for (int j = 0; j < 4; ++j) acc[i][j] = (f32x4){0.f, 0.f, 0.f, 0.f};

  const unsigned short* wcb = wc1 + ((size_t)b * 64 + (pd << 5) + (ph << 3) + (pw << 1)) * 8192;

  for (int td = 0; td < 2; ++td) {
    const char* Xp = (const char*)Xl + td * 25600;
    for (int th = 0; th < 2; ++th) {
      int hb = ph + th;
      for (int tw = 0; tw < 2; ++tw) {
        int wb2 = pw + tw;
        const unsigned short* wp = wcb + (size_t)((td << 4) + (th << 2) + tw) * 8192;
#pragma unroll
        for (int ksx = 0; ksx < 4; ++ksx) {
          int cq = (ksx << 2) + quad;
          short8 av[4], bv[4];
#pragma unroll
          for (int mt = 0; mt < 4; ++mt) {
            int pos = ((mt << 1) + (l16 >> 3) + hb) * 10 + (l16 & 7) + wb2;
            int pc = (cq & 8) | ((cq & 7) ^ (pos & 7));
            av[mt] = *(const short8*)(Xp + pos * 256 + (pc << 4));
          }
#pragma unroll
          for (int nt = 0; nt < 4; ++nt)
            bv[nt] = *(const short8*)(wp + (((cq << 6) + (nt << 4) + l16) << 3));
          __builtin_amdgcn_s_setprio(1);
#pragma unroll
          for (int mt = 0; mt < 4; ++mt)
#pragma unroll
            for (int nt = 0; nt < 4; ++nt)
              acc[mt][nt] = __builtin_amdgcn_mfma_f32_16x16x32_bf16(
                  av[mt], bv[nt], acc[mt][nt], 0, 0, 0);
          __builtin_amdgcn_s_setprio(0);
        }
      }
    }
  }

  __syncthreads();                      // Xl reads done -> stats scratch
  float* sbf = (float*)Xl;
  int rowb = (b * 16 + od) * 64;
#pragma unroll
  for (int nt = 0; nt < 4; ++nt) {
    int n = (nt << 4) + l16;
    float s = 0.f, q2 = 0.f;
#pragma unroll
    for (int mt = 0; mt < 4; ++mt) {
      int mh = (mt << 1) + (quad >> 1);
      int oh = (((hti << 3) + mh) << 1) + ph;
      size_t rb = (size_t)(rowb + oh) * 64;
#pragma unroll
      for (int r = 0; r < 4; ++r) {
        float v = acc[mt][nt][r];
        int ow = (((wti << 3) + ((quad & 1) << 2) + r) << 1) + pw;
        outb[(rb + ow) * 64 + n] = f2b(v);
        s += v; q2 += v * v;
      }
    }
    s += __shfl_xor(s, 16); s += __shfl_xor(s, 32);
    q2 += __shfl_xor(q2, 16); q2 += __shfl_xor(q2, 32);
    if (quad == 0) { sbf[wid * 128 + n] = s; sbf[wid * 128 + 64 + n] = q2; }
  }
  __syncthreads();
  if (tid < 64) {
    float s = sbf[tid] + sbf[128 + tid] + sbf[256 + tid] + sbf[384 + tid];
    float q2 = sbf[64 + tid] + sbf[192 + tid] + sbf[320 + tid] + sbf[448 + tid];
    int sl = (blockIdx.x & 7) << 7;
    atomicAdd(&sums[sl + tid], s);
    atomicAdd(&sums[sl + 64 + tid], q2);
  }
}

// ---------------- conv2: 32x32x16 MFMA, (row-half x k-half) waves ----------------
__global__ __launch_bounds__(256) void hg_convf_k(
    const unsigned short* __restrict__ y1n, const unsigned short* __restrict__ skb,
    const unsigned short* __restrict__ wt, const unsigned short* __restrict__ zb,
    float* __restrict__ outf, float* __restrict__ sums) {
  __shared__ short Al[132 * 128];  // 33792 B, unpadded, chunk-swizzled
  __shared__ short Wl[64 * 128];   // 16384 B, unpadded, chunk-swizzled
  int tid = threadIdx.x;
  int xcd = blockIdx.x & 7, slot = blockIdx.x >> 3;
  int b = xcd & 3;
  int t = ((xcd >> 2) << 8) + slot;       // 0..511 tile within sample
  int m0 = (b << 16) + (t << 7);
  int od  = (t >> 5) & 15;
  int oh0 = (t << 1) & 63;
  int lane = tid & 63, l32 = lane & 31, lh = lane >> 5;
  int wid = tid >> 6;
  int wh = wid & 1;                   // row half: rows wh*64 .. +63
  int ks = wid >> 1;                  // k half: chunks ks*8 .. +7

  f32x16 acc[2][2];
#pragma unroll
  for (int e = 0; e < 16; ++e) {
    acc[0][0][e] = 0.f; acc[0][1][e] = 0.f; acc[1][0][e] = 0.f; acc[1][1][e] = 0.f;
  }

  const unsigned short* wb = wt + (size_t)b * 27 * 8192;

  for (int kd = 0; kd < 3; ++kd) {
    int ud = od + kd - 1;
    int dok = ((unsigned)ud < 16u);
    for (int kh = 0; kh < 3; ++kh) {
      __syncthreads();  // prior MFMAs done before Al/Wl overwrite
      for (int i = 0; i < 9; ++i) {
        int task = tid + (i << 8);
        if (task < 2112) {
          int pos = task >> 4, pq = task & 15;
          int q = (pq & 8) | ((pq & 7) ^ (pos & 7));  // logical chunk (involution)
          int g = (pos >= 66) ? 1 : 0;
          int uw = pos - (g ? 66 : 0) - 1;
          int uh = oh0 + g + kh - 1;
          const unsigned short* src = zb;
          if (dok && (unsigned)uh < 64u && (unsigned)uw < 64u) {
            size_t srow = (((size_t)(b * 16 + ud)) * 64 + uh) * 64 + uw;
            src = (q < 8) ? (y1n + srow * 64 + (q << 3))
                          : (skb + srow * 64 + ((q - 8) << 3));
          }
          gload16(src, (char*)Al + (((i << 8) + (tid & 192)) << 4));
        }
      }
      for (int kw = 0; kw < 3; ++kw) {
        if (kw) __syncthreads();
        int tap = (kd * 3 + kh) * 3 + kw;
        const unsigned short* wsrc = wb + (size_t)tap * 8192;
        {
          int co0 = tid >> 4, pq = tid & 15;
          for (int i = 0; i < 4; ++i) {
            int co = co0 + (i << 4);
            int q = (pq & 8) | ((pq & 7) ^ (co & 7));
            gload16(wsrc + co * 128 + (q << 3),
                    (char*)Wl + (((i << 8) + (tid & 192)) << 4));
          }
        }
        __syncthreads();
        // 4 K=16 steps x (2 m x 2 n) 32-tiles
#pragma unroll
        for (int kt = 0; kt < 4; ++kt) {
          int ch = (ks << 3) + (kt << 1) + lh;   // logical chunk 0..15
          short8 av[2], bv[2];
#pragma unroll
          for (int mt = 0; mt < 2; ++mt) {
            int r = (wh << 6) + (mt << 5) + l32;
            int pos = (r >> 6) * 66 + (r & 63) + kw;
            int pc = (ch & 8) | ((ch & 7) ^ (pos & 7));
            av[mt] = *(const short8*)((const char*)Al + pos * 256 + (pc << 4));
          }
#pragma unroll
          for (int nt = 0; nt < 2; ++nt) {
            int co = (nt << 5) + l32;
            int pc = (ch & 8) | ((ch & 7) ^ (co & 7));
            bv[nt] = *(const short8*)((const char*)Wl + co * 256 + (pc << 4));
          }
#pragma unroll
          for (int mt = 0; mt < 2; ++mt)
#pragma unroll
            for (int nt = 0; nt < 2; ++nt)
              acc[mt][nt] = __builtin_amdgcn_mfma_f32_32x32x16_bf16(
                  av[mt], bv[nt], acc[mt][nt], 0, 0, 0);
        }
      }
    }
  }

  // ---- k-half combine: ks=1 dump to Al (16 pieces x 128 slots x 16B, conflict-free) ----
  __syncthreads();                      // all MFMAs / Al reads done
  if (ks == 1) {
    char* base = (char*)Al + (((wh << 6) + lane) << 4);
#pragma unroll
    for (int mt = 0; mt < 2; ++mt)
#pragma unroll
      for (int nt = 0; nt < 2; ++nt)
#pragma unroll
        for (int r4 = 0; r4 < 4; ++r4) {
          f32x4 v = {acc[mt][nt][(r4 << 2)], acc[mt][nt][(r4 << 2) + 1],
                     acc[mt][nt][(r4 << 2) + 2], acc[mt][nt][(r4 << 2) + 3]};
          *(f32x4*)(base + ((((mt << 1) + nt) << 2) + r4) * 2048) = v;
        }
  }
  __syncthreads();
  float* sbf = (float*)Wl;              // stats scratch (disjoint from Al)
  if (ks == 0) {
    const char* base = (const char*)Al + (((wh << 6) + lane) << 4);
#pragma unroll
    for (int mt = 0; mt < 2; ++mt)
#pragma unroll
      for (int nt = 0; nt < 2; ++nt)
#pragma unroll
        for (int r4 = 0; r4 < 4; ++r4) {
          f32x4 v = *(const f32x4*)(base + ((((mt << 1) + nt) << 2) + r4) * 2048);
#pragma unroll
          for (int j = 0; j < 4; ++j) acc[mt][nt][(r4 << 2) + j] += v[j];
        }
    // write + stats. C/D: col = lane&31, row = (reg&3) + 8*(reg>>2) + 4*lh
#pragma unroll
    for (int nt = 0; nt < 2; ++nt) {
      int n = (nt << 5) + l32;
      float s = 0.f, q2 = 0.f;
#pragma unroll
      for (int mt = 0; mt < 2; ++mt) {
        int rbase = m0 + (wh << 6) + (mt << 5) + (lh << 2);
#pragma unroll
        for (int r = 0; r < 16; ++r) {
          float v = acc[mt][nt][r];
          int row = rbase + (r & 3) + ((r >> 2) << 3);
          outf[(size_t)row * 64 + n] = v;
          s += v; q2 += v * v;
        }
      }
      s += __shfl_xor(s, 32);
      q2 += __shfl_xor(q2, 32);
      if (lh == 0) { sbf[(wh << 7) + n] = s; sbf[(wh << 7) + 64 + n] = q2; }
    }
  }
  __syncthreads();
  if (tid < 64) {
    float s = sbf[tid] + sbf[128 + tid];
    float q2 = sbf[64 + tid] + sbf[192 + tid];
    int sl = (blockIdx.x & 7) << 7;
    atomicAdd(&sums[sl + tid], s);
    atomicAdd(&sums[sl + 64 + tid], q2);
  }
}

// ---------------- fast-path BN1+ReLU in place on bf16 y1, fin8 folded ----------------
__global__ __launch_bounds__(256) void hg_bnbf_k(unsigned short* __restrict__ y,
                                                 const float* __restrict__ sb,
                                                 const float* __restrict__ gm,
                                                 const float* __restrict__ bt) {
  __shared__ float sc[64], sh[64];
  int tid = threadIdx.x;
  if (tid < 64) {
    float s = 0.f, q2 = 0.f;
    for (int k = 0; k < 8; ++k) { s += sb[(k << 7) + tid]; q2 += sb[(k << 7) + 64 + tid]; }
    float invN = 1.f / 262144.f;
    float mean = s * invN;
    float var  = q2 * invN - mean * mean;
    float scl = gm[tid] * rsqrtf(var + 1e-3f);
    sc[tid] = scl; sh[tid] = bt[tid] - mean * scl;
  }
  __syncthreads();
  size_t i = ((size_t)blockIdx.x * 256 + tid) << 3;
  int c0 = (int)(i & 63);
  uint4 v = *(uint4*)(y + i);
  unsigned int u[4] = {v.x, v.y, v.z, v.w};
  for (int q = 0; q < 4; ++q) {
    int c = c0 + q * 2;
    float f0 = sc[c] * bf2f((unsigned short)(u[q] & 0xFFFFu)) + sh[c];
    float f1 = sc[c + 1] * bf2f((unsigned short)(u[q] >> 16)) + sh[c + 1];
    u[q] = pk2(f0 > 0.f ? f0 : 0.f, f1 > 0.f ? f1 : 0.f);
  }
  *(uint4*)(y + i) = make_uint4(u[0], u[1], u[2], u[3]);
}

// ---------------- fast-path BN2+ReLU on fp32 out, fin8 folded ----------------
__global__ __launch_bounds__(256) void hg_bnrf_k(float* __restrict__ y,
                                                 const float* __restrict__ sb,
                                                 const float* __restrict__ gm,
                                                 const float* __restrict__ bt) {
  __shared__ float sc[64], sh[64];
  int tid = threadIdx.x;
  if (tid < 64) {
    float s = 0.f, q2 = 0.f;
    for (int k = 0; k < 8; ++k) { s += sb[(k << 7) + tid]; q2 += sb[(k << 7) + 64 + tid]; }
    float invN = 1.f / 262144.f;
    float mean = s * invN;
    float var  = q2 * invN - mean * mean;
    float scl = gm[tid] * rsqrtf(var + 1e-3f);
    sc[tid] = scl; sh[tid] = bt[tid] - mean * scl;
  }
  __syncthreads();
  size_t i = (size_t)blockIdx.x * 256 + tid;  // float4 index
  int c4 = ((int)i & 15) << 2;
  float4 v = *(float4*)(y + i * 4);
  float f;
  f = sc[c4]     * v.x + sh[c4];     v.x = f > 0.f ? f : 0.f;
  f = sc[c4 + 1] * v.y + sh[c4 + 1]; v.y = f > 0.f ? f : 0.f;
  f = sc[c4 + 2] * v.z + sh[c4 + 2]; v.z = f > 0.f ? f : 0.f;
  f = sc[c4 + 3] * v.w + sh[c4 + 3]; v.w = f > 0.f ? f : 0.f;
  *(float4*)(y + i * 4) = v;
}

// ================= fallback path (unchanged, ws too small) =================
__global__ __launch_bounds__(256) void hg_wt_k(const float* __restrict__ w1,
                                               const float* __restrict__ w2,
                                               unsigned short* __restrict__ wt1,
                                               unsigned short* __restrict__ wt2) {
  __shared__ short T[64 * ASTR];
  int blk = blockIdx.x;
  int sel = blk >= 108;
  const float* w = sel ? w2 : w1;
  unsigned short* wt = sel ? wt2 : wt1;
  int bt = sel ? blk - 108 : blk;
  const float* src = w + (size_t)bt * 8192;
  int tid = threadIdx.x;
  int co = tid & 63;
  int c0 = tid >> 6;
  for (int i = 0; i < 32; ++i) {
    int ci = c0 + (i << 2);
    T[co * ASTR + ci] = (short)f2b(src[(size_t)ci * 64 + co]);
  }
  __syncthreads();
  unsigned short* dst = wt + (size_t)bt * 8192;
  for (int i = 0; i < 4; ++i) {
    int task = tid + (i << 8);
    int row = task >> 4, q = task & 15;
    *(uint4*)(dst + row * 128 + (q << 3)) = *(const uint4*)&T[row * ASTR + (q << 3)];
  }
}

__global__ __launch_bounds__(256) void hg_conv_o_k(
    const float* __restrict__ xf, const unsigned short* __restrict__ y1n,
    const float* __restrict__ skip, const float* __restrict__ wf,
    const unsigned short* __restrict__ wt, const float* __restrict__ bn,
    unsigned short* __restrict__ outb, float* __restrict__ outf,
    int mode, int has_wt) {
  __shared__ short Al[132 * ASTR];
  __shared__ short Wl[64 * WSTR];
  __shared__ float sbl[128];
  int tid = threadIdx.x;
  int xcd = blockIdx.x & 7, slot = blockIdx.x >> 3;
  int b = xcd & 3;
  int t = ((xcd >> 2) << 8) + slot;
  int m0 = (b << 16) + (t << 7);
  int od  = (t >> 5) & 15;
  int oh0 = (t << 1) & 63;
  int lane = tid & 63, quad = lane >> 4, l16 = lane & 15;
  int wm = (tid >> 6) << 5;

  if (mode == 1 && tid < 128) sbl[tid] = bn[tid];

  f32x4 acc[2][4];
  for (int i = 0; i < 2; ++i)
    for (int j = 0; j < 4; ++j) acc[i][j] = (f32x4){0.f, 0.f, 0.f, 0.f};

  const float* wbf = wf + (size_t)b * 27 * 8192;
  const unsigned short* wbt = wt + (size_t)b * 27 * 8192;

  for (int kd = 0; kd < 3; ++kd) {
    int ud = od + kd - 1;
    int dok = (ud >= 0 && ud < 16);
    for (int kh = 0; kh < 3; ++kh) {
      __syncthreads();
      for (int i = 0; i < 9; ++i) {
        int task = tid + (i << 8);
        if (task < 2112) {
          int chunk = task & 15;
          int pos = task >> 4;
          int g = (pos >= 66) ? 1 : 0;
          int uwi = pos - (g ? 66 : 0);
          int uh = oh0 + g + kh - 1;
          int uw = uwi - 1;
          uint4 val = make_uint4(0u, 0u, 0u, 0u);
          if (dok && (unsigned)uh < 64u && (unsigned)uw < 64u) {
            if (mode == 0) {
              size_t src = ((((size_t)(b * 8 + (ud >> 1))) * 32 + (uh >> 1)) * 32 +
                            (uw >> 1)) * 128 + (chunk << 3);
              float4 f0 = *(const float4*)(xf + src);
              float4 f1 = *(const float4*)(xf + src + 4);
              val.x = pk2(f0.x, f0.y); val.y = pk2(f0.z, f0.w);
              val.z = pk2(f1.x, f1.y); val.w = pk2(f1.z, f1.w);
            } else {
              size_t srow = (((size_t)(b * 16 + ud)) * 64 + uh) * 64 + uw;
              if (chunk < 8) {
                uint4 raw = *(const uint4*)(y1n + srow * 64 + (chunk << 3));
                unsigned int u[4] = {raw.x, raw.y, raw.z, raw.w};
                unsigned int o[4];
                int c0 = chunk << 3;
                for (int q = 0; q < 4; ++q) {
                  int c = c0 + q * 2;
                  float f0 = sbl[c] * bf2f((unsigned short)(u[q] & 0xFFFFu)) + sbl[64 + c];
                  float f1 = sbl[c + 1] * bf2f((unsigned short)(u[q] >> 16)) + sbl[64 + c + 1];
                  o[q] = pk2(f0 > 0.f ? f0 : 0.f, f1 > 0.f ? f1 : 0.f);
                }
                val = make_uint4(o[0], o[1], o[2], o[3]);
              } else {
                const float* sp = skip + srow * 64 + ((chunk - 8) << 3);
                float4 f0 = *(const float4*)(sp);
                float4 f1 = *(const float4*)(sp + 4);
                val.x = pk2(f0.x, f0.y); val.y = pk2(f0.z, f0.w);
                val.z = pk2(f1.x, f1.y); val.w = pk2(f1.z, f1.w);
              }
            }
          }
          *(uint4*)&Al[pos * ASTR + (chunk << 3)] = val;
        }
      }
      for (int kw = 0; kw < 3; ++kw) {
        if (kw) __syncthreads();
        int tap = (kd * 3 + kh) * 3 + kw;
        if (has_wt) {
          const unsigned short* wsrc = wbt + (size_t)tap * 8192;
          for (int i = 0; i < 4; ++i) {
            int task = tid + (i << 8);
            int co = task >> 4, q = task & 15;
            *(uint4*)&Wl[co * WSTR + (q << 3)] = *(const uint4*)(wsrc + co * 128 + (q << 3));
          }
        } else {
          const float* wp = wbf + (size_t)tap * 8192 + (tid & 63);
          int wco = tid & 63;
          int ci0 = (tid >> 6) << 5;
          for (int c = 0; c < 32; c += 2) {
            float f0 = wp[(size_t)(ci0 + c) * 64];
            float f1 = wp[(size_t)(ci0 + c + 1) * 64];
            *(unsigned int*)&Wl[wco * WSTR + ci0 + c] = pk2(f0, f1);
          }
        }
        __syncthreads();
        for (int k0 = 0; k0 < 128; k0 += 32) {
          int kk = k0 + (quad << 3);
          union { uint4 u; short8 s; } cv;
          short8 av[2];
          for (int mt = 0; mt < 2; ++mt) {
            int r = wm + (mt << 4) + l16;
            int g = r >> 6, ow = r & 63;
            cv.u = *(const uint4*)&Al[(g * 66 + ow + kw) * ASTR + kk];
            av[mt] = cv.s;
          }
          short8 bv[4];
          for (int nt = 0; nt < 4; ++nt) {
            int base = ((nt << 4) + l16) * WSTR + kk;
            uint2 lo = *(const uint2*)&Wl[base];
            uint2 hi = *(const uint2*)&Wl[base + 4];
            cv.u = make_uint4(lo.x, lo.y, hi.x, hi.y);
            bv[nt] = cv.s;
          }
          for (int mt = 0; mt < 2; ++mt)
            for (int nt = 0; nt < 4; ++nt)
              acc[mt][nt] = __builtin_amdgcn_mfma_f32_16x16x32_bf16(
                  av[mt], bv[nt], acc[mt][nt], 0, 0, 0);
        }
      }
    }
  }

  for (int mt = 0; mt < 2; ++mt) {
    int mbase = m0 + wm + (mt << 4) + (quad << 2);
    for (int nt = 0; nt < 4; ++nt) {
      int n = (nt << 4) + l16;
      for (int r = 0; r < 4; ++r) {
        float v = acc[mt][nt][r];
        size_t o = (size_t)(mbase + r) * 64 + n;
        if (mode == 0) outb[o] = f2b(v);
        else outf[o] = v;
      }
    }
  }
}

__global__ void hg_zero_k(float* __restrict__ p, int n) {
  for (int i = threadIdx.x; i < n; i += 256) p[i] = 0.f;
}

__global__ __launch_bounds__(256) void hg_stats_k(const unsigned short* __restrict__ yb,
                                                  const float* __restrict__ yf, int isf,
                                                  float* __restrict__ sums) {
  int t = threadIdx.x;
  int c = t & 63;
  int r0 = blockIdx.x * 4 + (t >> 6);
  float sum = 0.f, ss = 0.f;
  for (int r = r0; r < 262144; r += 4096) {
    size_t idx = (size_t)r * 64 + c;
    float v = isf ? yf[idx] : bf2f(yb[idx]);
    sum += v; ss += v * v;
  }
  atomicAdd(&sums[c], sum);
  atomicAdd(&sums[64 + c], ss);
}

__global__ void hg_fin_k(float* __restrict__ sb, const float* __restrict__ gm,
                         const float* __restrict__ bt) {
  int c = threadIdx.x;  // 64
  float invN = 1.f / 262144.f;
  float mean = sb[c] * invN;
  float var  = sb[64 + c] * invN - mean * mean;
  float sc = gm[c] * rsqrtf(var + 1e-3f);
  sb[c] = sc;
  sb[64 + c] = bt[c] - mean * sc;
}

__global__ __launch_bounds__(256) void hg_bnb_k(unsigned short* __restrict__ y,
                                                const float* __restrict__ sb) {
  size_t i = ((size_t)blockIdx.x * 256 + threadIdx.x) << 3;
  int c0 = (int)(i & 63);
  uint4 v = *(uint4*)(y + i);
  unsigned int u[4] = {v.x, v.y, v.z, v.w};
  for (int q = 0; q < 4; ++q) {
    int c = c0 + q * 2;
    float f0 = sb[c] * bf2f((unsigned short)(u[q] & 0xFFFFu)) + sb[64 + c];
    float f1 = sb[c + 1] * bf2f((unsigned short)(u[q] >> 16)) + sb[64 + c + 1];
    u[q] = pk2(f0 > 0.f ? f0 : 0.f, f1 > 0.f ? f1 : 0.f);
  }
  *(uint4*)(y + i) = make_uint4(u[0], u[1], u[2], u[3]);
}

__global__ __launch_bounds__(256) void hg_bnrelu_f_k(float* __restrict__ y,
                                                     const float* __restrict__ sb) {
  size_t i = (size_t)blockIdx.x * 256 + threadIdx.x;  // float4 index
  int c4 = ((int)i & 15) << 2;
  float4 v = *(float4*)(y + i * 4);
  float f;
  f = sb[c4]     * v.x + sb[64 + c4];     v.x = f > 0.f ? f : 0.f;
  f = sb[c4 + 1] * v.y + sb[64 + c4 + 1]; v.y = f > 0.f ? f : 0.f;
  f = sb[c4 + 2] * v.z + sb[64 + c4 + 2]; v.z = f > 0.f ? f : 0.f;
  f = sb[c4 + 3] * v.w + sb[64 + c4 + 3]; v.w = f > 0.f ? f : 0.f;
  *(float4*)(y + i * 4) = v;
}

extern "C" void kernel_launch(void* const* d_in, const int* in_sizes, int n_in,
                              void* d_out, int out_size, void* d_ws, size_t ws_size,
                              hipStream_t stream) {
  (void)out_size;
  int ix = 0, iw1 = 1, iw2 = 2, isk = 3, ig1 = 4, ib1 = 5, ig2 = 6, ib2 = 7;
  if (n_in >= 9 && in_sizes[0] == 4194304 && in_sizes[1] == 884736 &&
      in_sizes[3] == 16777216 && in_sizes[4] == 64) {
    // insertion order
  } else if (n_in >= 9 && in_sizes[0] == 64 && in_sizes[4] == 16777216 &&
             in_sizes[6] == 884736 && in_sizes[8] == 4194304) {
    ib1 = 0; ib2 = 1; ig1 = 2; ig2 = 3; isk = 4; iw1 = 6; iw2 = 7; ix = 8;
  } else {
    return;
  }
  if (ws_size < (32ull << 20) + 2048ull) return;

  const float* x    = (const float*)d_in[ix];
  const float* w1   = (const float*)d_in[iw1];
  const float* w2   = (const float*)d_in[iw2];
  const float* skip = (const float*)d_in[isk];
  const float* g1   = (const float*)d_in[ig1];
  const float* b1   = (const float*)d_in[ib1];
  const float* g2   = (const float*)d_in[ig2];
  const float* b2   = (const float*)d_in[ib2];
  float* out = (float*)d_out;

  // fast-path layout
  const size_t OFF_SUMS = 32ull << 20;            // 8 KiB: 2 layers x 8 slots x 128 f32
  const size_t OFF_ZB   = OFF_SUMS + 8192;        // zero16 region (256 B)
  const size_t OFF_WT2  = OFF_ZB + 256;           // wt2 transposed
  const size_t OFF_XB   = OFF_WT2 + 2ull * 1769472;
  const size_t OFF_SKB  = OFF_XB + 8388608;       // 4194304 bf16
  const size_t OFF_WC1  = OFF_SKB + 33554432;     // 16777216 bf16
  const size_t NEED     = OFF_WC1 + 4194304;      // ~79.4 MB

  unsigned short* y1 = (unsigned short*)d_ws;     // 32 MiB bf16

  if (ws_size >= NEED) {
    // -------- fast path: 5 dispatches --------
    float* sums  = (float*)((char*)d_ws + OFF_SUMS);
    float* sums1 = sums;                          // 8 slots x 128
    float* sums2 = sums + 1024;                   // 8 slots x 128
    unsigned short* zb  = (unsigned short*)((char*)d_ws + OFF_ZB);
    unsigned short* wt2 = (unsigned short*)((char*)d_ws + OFF_WT2);
    unsigned short* xb  = (unsigned short*)((char*)d_ws + OFF_XB);
    unsigned short* skb = (unsigned short*)((char*)d_ws + OFF_SKB);
    unsigned short* wc1 = (unsigned short*)((char*)d_ws + OFF_WC1);

    hg_prep_k<<<10605, 256, 0, stream>>>(x, skip, w1, w2, xb, skb, wt2, wc1, sums);
    hg_c1p_k<<<1024, 256, 0, stream>>>(xb, wc1, zb, y1, sums1);
    hg_bnbf_k<<<8192, 256, 0, stream>>>(y1, sums1, g1, b1);
    hg_convf_k<<<2048, 256, 0, stream>>>(y1, skb, wt2, zb, out, sums2);
    hg_bnrf_k<<<16384, 256, 0, stream>>>(out, sums2, g2, b2);
  } else {
    // -------- fallback: R9 path (original layout) --------
    float* sums  = (float*)((char*)d_ws + (32ull << 20));
    float* sums1 = sums;
    float* sums2 = sums + 128;
    unsigned short* wt1 = (unsigned short*)((char*)d_ws + (32ull << 20) + 2048ull);
    unsigned short* wt2 = wt1 + 884736ull;
    const size_t WS_NEED = (32ull << 20) + 2048ull + 2ull * 884736ull * 2ull;
    int has_wt = (ws_size >= WS_NEED) ? 1 : 0;

    hg_zero_k<<<1, 256, 0, stream>>>(sums, 512);
    if (has_wt) hg_wt_k<<<216, 256, 0, stream>>>(w1, w2, wt1, wt2);
    hg_conv_o_k<<<2048, 256, 0, stream>>>(x, y1, skip, w1, wt1, sums1, y1, out, 0, has_wt);
    hg_stats_k<<<1024, 256, 0, stream>>>(y1, out, 0, sums1);
    hg_fin_k<<<1, 64, 0, stream>>>(sums1, g1, b1);
    hg_conv_o_k<<<2048, 256, 0, stream>>>(x, y1, skip, w2, wt2, sums1, y1, out, 1, has_wt);
    hg_stats_k<<<1024, 256, 0, stream>>>(y1, out, 1, sums2);
    hg_fin_k<<<1, 64, 0, stream>>>(sums2, g2, b2);
    hg_bnrelu_f_k<<<16384, 256, 0, stream>>>(out, sums2);
  }
}